// Round 5
// baseline (3967.847 us; speedup 1.0000x reference)
//
#include <hip/hip_runtime.h>
#include <hip/hip_bf16.h>

typedef unsigned short u16;
typedef __attribute__((ext_vector_type(8))) __bf16 bf16x8;
typedef __attribute__((ext_vector_type(4))) float f32x4;

#define HW_ 320
#define DIM_ 256
#define HID_ 1024
#define SCALE_ 0.1767766952966369f
#define LDP 72
#define NEGINF_ -30000.0f

__device__ __forceinline__ float b2f(u16 u){
  union{unsigned int i; float f;} z; z.i=((unsigned int)u)<<16; return z.f;
}
__device__ __forceinline__ u16 f2b(float f){
  union{float f; unsigned int i;} z; z.f=f;
  return (u16)((z.i + 0x7fffu + ((z.i>>16)&1u))>>16);
}
// f2b with NaN/Inf sentinel substitution (diagnostic: absmax names the stage)
__device__ __forceinline__ u16 f2b_s(float f, float sub){
  union{float f; unsigned int i;} z; z.f=f;
  if ((z.i & 0x7F800000u) == 0x7F800000u) z.f = sub;
  return (u16)((z.i + 0x7fffu + ((z.i>>16)&1u))>>16);
}

// ---------------- prep: fp32 weight -> bf16 transposed ----------------
__global__ void k_transpose(const float* __restrict__ src, u16* __restrict__ dst, int K, int N){
  int i = blockIdx.x*256 + threadIdx.x;
  if (i < K*N){ int k = i / N, n = i - k*N; dst[(size_t)n*K + k] = f2b(src[i]); }
}
__global__ void k_qkvbias(const float* __restrict__ bq, const float* __restrict__ bkv, float* __restrict__ dst){
  int i = blockIdx.x*256 + threadIdx.x;
  if (i < 768) dst[i] = (i<256) ? bq[i] : bkv[i-256];
}

// ---------------- per-row LN stats ----------------
__global__ __launch_bounds__(256) void k_stats_f32(const float* __restrict__ x, float2* __restrict__ st){
  int tid = threadIdx.x, lane = tid & 63;
  int t = blockIdx.x*4 + (tid>>6);
  float4 v = *(const float4*)(x + (size_t)t*DIM_ + lane*4);
  float s  = v.x+v.y+v.z+v.w;
  float ss = v.x*v.x+v.y*v.y+v.z*v.z+v.w*v.w;
  for (int m=1;m<64;m<<=1){ s += __shfl_xor(s,m,64); ss += __shfl_xor(ss,m,64); }
  float mean = s*(1.0f/DIM_);
  float var  = ss*(1.0f/DIM_) - mean*mean;
  if (var < 0.f) var = 0.f;
  if (lane==0) st[t] = make_float2(mean, rsqrtf(var + 1e-5f));
}
__global__ __launch_bounds__(256) void k_stats_bf16(const u16* __restrict__ x, float2* __restrict__ st){
  int tid = threadIdx.x, lane = tid & 63;
  int t = blockIdx.x*4 + (tid>>6);
  uint2 u = *(const uint2*)(x + (size_t)t*DIM_ + lane*4);
  float v0=b2f((u16)(u.x&0xffff)), v1=b2f((u16)(u.x>>16));
  float v2=b2f((u16)(u.y&0xffff)), v3=b2f((u16)(u.y>>16));
  float s  = v0+v1+v2+v3;
  float ss = v0*v0+v1*v1+v2*v2+v3*v3;
  for (int m=1;m<64;m<<=1){ s += __shfl_xor(s,m,64); ss += __shfl_xor(ss,m,64); }
  float mean = s*(1.0f/DIM_);
  float var  = ss*(1.0f/DIM_) - mean*mean;
  if (var < 0.f) var = 0.f;
  if (lane==0) st[t] = make_float2(mean, rsqrtf(var + 1e-5f));
}

// ---------------- generic MFMA GEMM: C = A[M,K] * Bt[N,K]^T ----------------
// ALN 0: A bf16 rows (owin / gband).
// ALN 1: A = x (fp32), LN inline + window-gather; a_off = window base.
// ALN 2: A = x1 (bf16), LN inline, srow = clamp(a_off + local).
// EPI 0: qkv scatter -> Q/K/V bf16 (biasf fp32[768]).
// EPI 1: + biasf + resf(x fp32) + window-reverse -> O0 = x1 bf16 (global rows).
// EPI 2: + biasf, gelu -> O0 = fband bf16 [local,1024].
// EPI 3: + biasf + resb(x1 bf16, rows o_off+local) -> Of fp32 (d_out).
template<int EPI, int ALN>
__global__ __launch_bounds__(256) void k_gemm(
    const void* __restrict__ Av, const u16* __restrict__ Bt, int K,
    const float2* __restrict__ stats, const float* __restrict__ lng, const float* __restrict__ lnb,
    const float* __restrict__ biasf,
    const float* __restrict__ resf, const u16* __restrict__ resb,
    u16* __restrict__ O0, u16* __restrict__ O1, u16* __restrict__ O2,
    float* __restrict__ Of,
    int a_off, int o_off)
{
  __shared__ u16 Al[128*LDP];
  __shared__ u16 Bl[128*LDP];
  int tid = threadIdx.x;
  int m0 = blockIdx.y*128, n0 = blockIdx.x*128;
  int w = tid>>6, lane = tid&63, lr = lane&15, lg = lane>>4;
  int wrow = (w>>1)*64, wcol = (w&1)*64;
  f32x4 zero = {0.f,0.f,0.f,0.f};
  f32x4 acc[4][4];
  #pragma unroll
  for (int i=0;i<4;++i)
    #pragma unroll
    for (int j=0;j<4;++j) acc[i][j]=zero;

  for (int kt=0; kt<K; kt+=64){
    #pragma unroll
    for (int it=0; it<4; ++it){
      int vi = tid + it*256;
      int row = vi>>3, cv = (vi&7)*8;
      *(bf16x8*)&Bl[row*LDP+cv] = *(const bf16x8*)(Bt + (size_t)(n0+row)*K + kt + cv);
      if constexpr (ALN==0){
        const u16* A = (const u16*)Av;
        *(bf16x8*)&Al[row*LDP+cv] = *(const bf16x8*)(A + (size_t)(m0+row)*K + kt + cv);
      } else {
        int srow;
        if constexpr (ALN==1){
          int rW = m0+row;
          int q100 = rW/100;
          int n = rW - q100*100;
          int win = a_off + q100;
          srow = ((win>>5)*10 + n/10)*HW_ + (win&31)*10 + (n%10);
        } else {
          srow = a_off + m0 + row;
          srow = srow < 0 ? 0 : (srow > 102399 ? 102399 : srow);
        }
        float2 st = stats[srow];
        float va[8];
        if constexpr (ALN==1){
          const float* A = (const float*)Av;
          float4 f0 = *(const float4*)(A + (size_t)srow*DIM_ + kt + cv);
          float4 f1 = *(const float4*)(A + (size_t)srow*DIM_ + kt + cv + 4);
          va[0]=f0.x; va[1]=f0.y; va[2]=f0.z; va[3]=f0.w;
          va[4]=f1.x; va[5]=f1.y; va[6]=f1.z; va[7]=f1.w;
        } else {
          const u16* A = (const u16*)Av;
          uint4 u = *(const uint4*)(A + (size_t)srow*DIM_ + kt + cv);
          const unsigned* up = (const unsigned*)&u;
          #pragma unroll
          for (int e=0;e<4;++e){ va[2*e]=b2f((u16)(up[e]&0xffff)); va[2*e+1]=b2f((u16)(up[e]>>16)); }
        }
        float4 g0 = *(const float4*)(lng + kt + cv);
        float4 g1 = *(const float4*)(lng + kt + cv + 4);
        float4 c0 = *(const float4*)(lnb + kt + cv);
        float4 c1 = *(const float4*)(lnb + kt + cv + 4);
        float gg[8] = {g0.x,g0.y,g0.z,g0.w,g1.x,g1.y,g1.z,g1.w};
        float cc[8] = {c0.x,c0.y,c0.z,c0.w,c1.x,c1.y,c1.z,c1.w};
        uint4 pk;
        unsigned* pp = (unsigned*)&pk;
        #pragma unroll
        for (int e=0;e<4;++e){
          unsigned lo = f2b((va[2*e]  -st.x)*st.y*gg[2*e]   + cc[2*e]);
          unsigned hi = f2b((va[2*e+1]-st.x)*st.y*gg[2*e+1] + cc[2*e+1]);
          pp[e] = lo | (hi<<16);
        }
        *(uint4*)&Al[row*LDP+cv] = pk;
      }
    }
    __syncthreads();
    #pragma unroll
    for (int k0=0;k0<64;k0+=32){
      bf16x8 af[4], bfr[4];
      #pragma unroll
      for (int i=0;i<4;++i) af[i]  = *(const bf16x8*)&Al[(wrow+i*16+lr)*LDP + k0 + lg*8];
      #pragma unroll
      for (int j=0;j<4;++j) bfr[j] = *(const bf16x8*)&Bl[(wcol+j*16+lr)*LDP + k0 + lg*8];
      #pragma unroll
      for (int i=0;i<4;++i)
        #pragma unroll
        for (int j=0;j<4;++j)
          acc[i][j] = __builtin_amdgcn_mfma_f32_16x16x32_bf16(af[i], bfr[j], acc[i][j],0,0,0);
    }
    __syncthreads();
  }

  #pragma unroll
  for (int i=0;i<4;++i){
    #pragma unroll
    for (int j=0;j<4;++j){
      #pragma unroll
      for (int r=0;r<4;++r){
        int grow = m0 + wrow + i*16 + lg*4 + r;
        int gcol = n0 + wcol + j*16 + lr;
        float v = acc[i][j][r];
        if constexpr (EPI==0){
          v += biasf[gcol];
          int winl = grow/100, n = grow - winl*100;
          int part = gcol>>8, c = gcol&255;
          size_t idx = ((size_t)(winl*8 + (c>>5))*100 + n)*32 + (c&31);
          if (part==0)      O0[idx] = f2b_s(v*SCALE_, 10000.f);
          else if (part==1) O1[idx] = f2b_s(v, 10000.f);
          else              O2[idx] = f2b_s(v, 10000.f);
        } else if constexpr (EPI==1){
          int win = grow/100, n = grow - win*100;
          int wy = win>>5, wxx = win&31;
          int py = n/10, px = n - py*10;
          size_t t = (size_t)((wy*10+py)*HW_ + wxx*10 + px);
          float o = v + biasf[gcol] + resf[t*DIM_ + gcol];
          O0[t*DIM_ + gcol] = f2b_s(o, 30000.f);
        } else if constexpr (EPI==2){
          float o = v + biasf[gcol];
          o = 0.5f*o*(1.0f + erff(o*0.70710678118654752f));
          O0[(size_t)grow*HID_ + gcol] = f2b_s(o, 40000.f);
        } else {
          size_t t = (size_t)(o_off + grow);
          float o = v + biasf[gcol] + b2f(resb[t*DIM_ + gcol]);
          union{float f; unsigned int i;} z; z.f=o;
          if ((z.i & 0x7F800000u) == 0x7F800000u) o = 60000.f;
          Of[t*DIM_ + gcol] = o;
        }
      }
    }
  }
}

// ---------------- window attention: one block per (local window, head) ----------------
__global__ __launch_bounds__(256) void k_attn(
    const u16* __restrict__ Q, const u16* __restrict__ Kb, const u16* __restrict__ Vb,
    const float* __restrict__ rpb, u16* __restrict__ Ow, int w_base)
{
  __shared__ float rpb_s[361];
  __shared__ u16 p_lds[112*136];
  __shared__ u16 v_t[32*136];
  int tid = threadIdx.x;
  int wh = blockIdx.x;
  int head = wh & 7, winl = wh >> 3;
  for (int i=tid;i<361;i+=256) rpb_s[i] = rpb[i*8+head];
  for (int i=tid;i<112*136;i+=256) p_lds[i] = 0;
  for (int i=tid;i<32*136;i+=256) v_t[i] = 0;
  __syncthreads();
  const u16* vbase = Vb + (size_t)wh*3200;
  for (int i=tid;i<3200;i+=256){ int m=i>>5, d=i&31; v_t[d*136+m] = vbase[i]; }

  int w = tid>>6, lane = tid&63, lr = lane&15, lg = lane>>4;
  const u16* qbase = Q  + (size_t)wh*3200;
  const u16* kbase = Kb + (size_t)wh*3200;
  f32x4 zero = {0.f,0.f,0.f,0.f};
  bf16x8 aq[2];
  #pragma unroll
  for (int rt=0;rt<2;++rt){
    int qr = w*32 + rt*16 + lr; if (qr>99) qr=99;
    aq[rt] = *(const bf16x8*)(qbase + qr*32 + lg*8);
  }
  f32x4 s[2][7];
  #pragma unroll
  for (int ct=0;ct<7;++ct){
    int kr = ct*16 + lr; if (kr>99) kr=99;
    bf16x8 bk = *(const bf16x8*)(kbase + kr*32 + lg*8);
    s[0][ct] = __builtin_amdgcn_mfma_f32_16x16x32_bf16(aq[0], bk, zero,0,0,0);
    s[1][ct] = __builtin_amdgcn_mfma_f32_16x16x32_bf16(aq[1], bk, zero,0,0,0);
  }
  #pragma unroll
  for (int rt=0;rt<2;++rt){
    #pragma unroll
    for (int ct=0;ct<7;++ct){
      #pragma unroll
      for (int r=0;r<4;++r){
        int n = w*32 + rt*16 + lg*4 + r;
        int m = ct*16 + lr;
        float sv = s[rt][ct][r];
        if (m<100 && n<100)
          sv += rpb_s[(n/10 - m/10 + 9)*19 + (n%10 - m%10 + 9)];
        if (m>=100) sv = NEGINF_;
        s[rt][ct][r] = sv;
      }
    }
  }
  #pragma unroll
  for (int rt=0;rt<2;++rt){
    #pragma unroll
    for (int r=0;r<4;++r){
      float mx = NEGINF_;
      #pragma unroll
      for (int ct=0;ct<7;++ct) mx = fmaxf(mx, s[rt][ct][r]);
      #pragma unroll
      for (int msk=1;msk<16;msk<<=1) mx = fmaxf(mx, __shfl_xor(mx,msk,64));
      float sm = 0.f;
      #pragma unroll
      for (int ct=0;ct<7;++ct){ float p = expf(s[rt][ct][r]-mx); s[rt][ct][r]=p; sm+=p; }
      #pragma unroll
      for (int msk=1;msk<16;msk<<=1) sm += __shfl_xor(sm,msk,64);
      float inv = 1.f/sm;
      int n = w*32 + rt*16 + lg*4 + r;
      if (n < 112){
        #pragma unroll
        for (int ct=0;ct<7;++ct) p_lds[n*136 + ct*16 + lr] = f2b(s[rt][ct][r]*inv);
      }
    }
  }
  __syncthreads();
  f32x4 o[2][2];
  o[0][0]=zero; o[0][1]=zero; o[1][0]=zero; o[1][1]=zero;
  #pragma unroll
  for (int k0=0;k0<128;k0+=32){
    bf16x8 ap[2];
    #pragma unroll
    for (int rt=0;rt<2;++rt){
      int pr = w*32 + rt*16 + lr; if (pr>111) pr=111;
      ap[rt] = *(const bf16x8*)&p_lds[pr*136 + k0 + lg*8];
    }
    #pragma unroll
    for (int dt=0;dt<2;++dt){
      bf16x8 bv = *(const bf16x8*)&v_t[(dt*16+lr)*136 + k0 + lg*8];
      o[0][dt] = __builtin_amdgcn_mfma_f32_16x16x32_bf16(ap[0], bv, o[0][dt],0,0,0);
      o[1][dt] = __builtin_amdgcn_mfma_f32_16x16x32_bf16(ap[1], bv, o[1][dt],0,0,0);
    }
  }
  int win_g = w_base + winl;
  #pragma unroll
  for (int rt=0;rt<2;++rt){
    #pragma unroll
    for (int dt=0;dt<2;++dt){
      #pragma unroll
      for (int r=0;r<4;++r){
        int n = w*32 + rt*16 + lg*4 + r;
        if (n<100)
          Ow[((size_t)(win_g*100+n))*DIM_ + head*32 + dt*16 + lr] = f2b_s(o[rt][dt][r], 20000.f);
      }
    }
  }
}

// ---------------- banded 3x3 depthwise conv + gelu ----------------
// fband: [10*320,1024] bf16 = scanlines [y0-1, y0+9). gband: [8*320,1024] bf16.
__global__ __launch_bounds__(256) void k_dwconv(const u16* __restrict__ f,
    const float* __restrict__ wgt, const float* __restrict__ bias, u16* __restrict__ g, int y0)
{
  int gid = blockIdx.x*256 + threadIdx.x;
  int p = gid >> 7;
  int cg = (gid & 127) << 3;
  int py = p/HW_, x = p - py*HW_;
  int y = y0 + py;
  float acc[8];
  #pragma unroll
  for (int c=0;c<8;++c) acc[c] = bias[cg+c];
  for (int ky=-1;ky<=1;++ky){
    int yy = y+ky; if (yy<0 || yy>=HW_) continue;
    int lrow = py + ky + 1;
    for (int kx=-1;kx<=1;++kx){
      int xx = x+kx; if (xx<0 || xx>=HW_) continue;
      uint4 u = *(const uint4*)(f + ((size_t)(lrow*HW_+xx))*HID_ + cg);
      int kk = (ky+1)*3 + (kx+1);
      float fv[8] = { b2f((u16)(u.x&0xffff)), b2f((u16)(u.x>>16)),
                      b2f((u16)(u.y&0xffff)), b2f((u16)(u.y>>16)),
                      b2f((u16)(u.z&0xffff)), b2f((u16)(u.z>>16)),
                      b2f((u16)(u.w&0xffff)), b2f((u16)(u.w>>16)) };
      #pragma unroll
      for (int c=0;c<8;++c) acc[c] += fv[c]*wgt[(cg+c)*9 + kk];
    }
  }
  u16 ov[8];
  #pragma unroll
  for (int c=0;c<8;++c){
    float v = acc[c];
    v = 0.5f*v*(1.0f + erff(v*0.70710678118654752f));
    ov[c] = f2b_s(v, 50000.f);
  }
  uint4 pack;
  pack.x = (unsigned)ov[0] | ((unsigned)ov[1]<<16);
  pack.y = (unsigned)ov[2] | ((unsigned)ov[3]<<16);
  pack.z = (unsigned)ov[4] | ((unsigned)ov[5]<<16);
  pack.w = (unsigned)ov[6] | ((unsigned)ov[7]<<16);
  *(uint4*)(g + ((size_t)p)*HID_ + cg) = pack;
}

extern "C" void kernel_launch(void* const* d_in, const int* in_sizes, int n_in,
                              void* d_out, int out_size, void* d_ws, size_t ws_size,
                              hipStream_t stream)
{
  (void)in_sizes; (void)n_in; (void)out_size; (void)ws_size;
  const float* x     = (const float*)d_in[0];
  const float* n1g   = (const float*)d_in[1];
  const float* n1b   = (const float*)d_in[2];
  const float* wq    = (const float*)d_in[3];
  const float* bq    = (const float*)d_in[4];
  const float* wkv   = (const float*)d_in[5];
  const float* bkv   = (const float*)d_in[6];
  const float* rpb   = (const float*)d_in[7];
  const float* projw = (const float*)d_in[8];
  const float* projb = (const float*)d_in[9];
  const float* n2g   = (const float*)d_in[10];
  const float* n2b   = (const float*)d_in[11];
  const float* l1w   = (const float*)d_in[12];
  const float* l1b   = (const float*)d_in[13];
  const float* dww   = (const float*)d_in[14];
  const float* dwb   = (const float*)d_in[15];
  const float* l2w   = (const float*)d_in[16];
  const float* l2b   = (const float*)d_in[17];

  char* ws = (char*)d_ws;
  // tables at bottom (3.2 MB)
  u16*   WqkvT   = (u16*)(ws + 0);              //   393,216 B
  u16*   projT   = (u16*)(ws + 393216);         //   131,072
  u16*   l1T     = (u16*)(ws + 524288);         //   524,288
  u16*   l2T     = (u16*)(ws + 1048576);        //   524,288
  float* qkvbias = (float*)(ws + 1572864);      //     3,072
  float2* stats1 = (float2*)(ws + 1576960);     //   819,200
  float2* stats2 = (float2*)(ws + 2396160);     //   819,200
  u16*   x1      = (u16*)(ws + 3276800);        // 52,428,800 -> 55,705,600
  char*  BR      = ws + 55705600;               // 11,796,480 -> 67,502,080 total
  u16* Qb    = (u16*)(BR + 0);                  // 3,276,800 each (64-window batch)
  u16* Kbuf  = (u16*)(BR + 3276800);
  u16* Vbuf  = (u16*)(BR + 6553600);
  u16* fband = (u16*)(BR + 0);                  // 6,553,600 (10*320*1024*2)
  u16* gband = (u16*)(BR + 6553600);            // 5,242,880 (8*320*1024*2)
  u16* owin  = (u16*)d_out;                     // bf16 scratch inside fp32 out buffer
  float* outp = (float*)d_out;

  // weight transposes (fp32 -> bf16) + bias table
  k_transpose<<<256, 256, 0, stream>>>(wq,   WqkvT,          256, 256);
  k_transpose<<<512, 256, 0, stream>>>(wkv,  WqkvT + 65536,  256, 512);
  k_transpose<<<256, 256, 0, stream>>>(projw, projT,         256, 256);
  k_transpose<<<1024,256, 0, stream>>>(l1w,  l1T,            256, 1024);
  k_transpose<<<1024,256, 0, stream>>>(l2w,  l2T,            1024, 256);
  k_qkvbias<<<3, 256, 0, stream>>>(bq, bkv, qkvbias);

  // LN1 stats
  k_stats_f32<<<25600, 256, 0, stream>>>(x, stats1);

  // attention in 16 batches of 64 windows
  for (int wb=0; wb<16; ++wb){
    k_gemm<0,1><<<dim3(6,50), 256, 0, stream>>>(x, WqkvT, 256,
        stats1, n1g, n1b, qkvbias, nullptr, nullptr, Qb, Kbuf, Vbuf, nullptr, wb*64, 0);
    k_attn<<<512, 256, 0, stream>>>(Qb, Kbuf, Vbuf, rpb, owin, wb*64);
  }
  // proj + residual(x fp32) + window reverse -> x1 bf16
  k_gemm<1,0><<<dim3(2,800), 256, 0, stream>>>(owin, projT, 256,
      nullptr, nullptr, nullptr, projb, x, nullptr, x1, nullptr, nullptr, nullptr, 0, 0);
  // LN2 stats (from x1 bf16)
  k_stats_bf16<<<25600, 256, 0, stream>>>(x1, stats2);
  // banded LeFF: 40 bands of 8 scanlines
  for (int b=0; b<40; ++b){
    int y0 = 8*b;
    k_gemm<2,2><<<dim3(8,25), 256, 0, stream>>>(x1, l1T, 256,
        stats2, n2g, n2b, l1b, nullptr, nullptr, fband, nullptr, nullptr, nullptr,
        (y0-1)*HW_, 0);
    k_dwconv<<<1280, 256, 0, stream>>>(fband, dww, dwb, gband, y0);
    k_gemm<3,0><<<dim3(2,20), 256, 0, stream>>>(gband, l2T, 1024,
        nullptr, nullptr, nullptr, l2b, nullptr, x1, nullptr, nullptr, nullptr, outp,
        0, y0*HW_);
  }
}

// Round 6
// 2447.826 us; speedup vs baseline: 1.6210x; 1.6210x over previous
//
#include <hip/hip_runtime.h>
#include <hip/hip_bf16.h>

typedef unsigned short u16;
typedef __attribute__((ext_vector_type(8))) __bf16 bf16x8;
typedef __attribute__((ext_vector_type(4))) float f32x4;

#define HW_ 320
#define DIM_ 256
#define HID_ 1024
#define SCALE_ 0.1767766952966369f
#define LDP 72
#define NEGINF_ -30000.0f

__device__ __forceinline__ float b2f(u16 u){
  union{unsigned int i; float f;} z; z.i=((unsigned int)u)<<16; return z.f;
}
__device__ __forceinline__ u16 f2b(float f){
  union{float f; unsigned int i;} z; z.f=f;
  return (u16)((z.i + 0x7fffu + ((z.i>>16)&1u))>>16);
}
__device__ __forceinline__ u16 f2b_s(float f, float sub){
  union{float f; unsigned int i;} z; z.f=f;
  if ((z.i & 0x7F800000u) == 0x7F800000u) z.f = sub;
  return (u16)((z.i + 0x7fffu + ((z.i>>16)&1u))>>16);
}

// ---------------- prep: fp32 weight -> bf16 transposed ----------------
__global__ void k_transpose(const float* __restrict__ src, u16* __restrict__ dst, int K, int N){
  int i = blockIdx.x*256 + threadIdx.x;
  if (i < K*N){ int k = i / N, n = i - k*N; dst[(size_t)n*K + k] = f2b(src[i]); }
}
__global__ void k_qkvbias(const float* __restrict__ bq, const float* __restrict__ bkv, float* __restrict__ dst){
  int i = blockIdx.x*256 + threadIdx.x;
  if (i < 768) dst[i] = (i<256) ? bq[i] : bkv[i-256];
}

// ---------------- per-row LN stats ----------------
__global__ __launch_bounds__(256) void k_stats_f32(const float* __restrict__ x, float2* __restrict__ st){
  int tid = threadIdx.x, lane = tid & 63;
  int t = blockIdx.x*4 + (tid>>6);
  float4 v = *(const float4*)(x + (size_t)t*DIM_ + lane*4);
  float s  = v.x+v.y+v.z+v.w;
  float ss = v.x*v.x+v.y*v.y+v.z*v.z+v.w*v.w;
  for (int m=1;m<64;m<<=1){ s += __shfl_xor(s,m,64); ss += __shfl_xor(ss,m,64); }
  float mean = s*(1.0f/DIM_);
  float var  = ss*(1.0f/DIM_) - mean*mean;
  if (var < 0.f) var = 0.f;
  if (lane==0) st[t] = make_float2(mean, rsqrtf(var + 1e-5f));
}
__global__ __launch_bounds__(256) void k_stats_bf16(const u16* __restrict__ x, float2* __restrict__ st){
  int tid = threadIdx.x, lane = tid & 63;
  int t = blockIdx.x*4 + (tid>>6);
  uint2 u = *(const uint2*)(x + (size_t)t*DIM_ + lane*4);
  float v0=b2f((u16)(u.x&0xffff)), v1=b2f((u16)(u.x>>16));
  float v2=b2f((u16)(u.y&0xffff)), v3=b2f((u16)(u.y>>16));
  float s  = v0+v1+v2+v3;
  float ss = v0*v0+v1*v1+v2*v2+v3*v3;
  for (int m=1;m<64;m<<=1){ s += __shfl_xor(s,m,64); ss += __shfl_xor(ss,m,64); }
  float mean = s*(1.0f/DIM_);
  float var  = ss*(1.0f/DIM_) - mean*mean;
  if (var < 0.f) var = 0.f;
  if (lane==0) st[t] = make_float2(mean, rsqrtf(var + 1e-5f));
}

// ---------------- generic MFMA GEMM: C = A[M,K] * Bt[N,K]^T ----------------
// ALN 0: A bf16 rows (owin / gband).
// ALN 1: A = x (fp32), LN inline + window-gather; a_off = window base.
// ALN 2: A = x1 (bf16), LN inline, srow = clamp(a_off + local).
// EPI 0: qkv scatter -> Q/K/V bf16 (biasf fp32[768]).
// EPI 1: + biasf + resf(x fp32) + window-reverse -> O0 = x1 bf16 (global rows).
// EPI 2: + biasf, gelu -> O0 = fband bf16 [local,1024].
// EPI 3: + biasf + resb(x1 bf16, rows o_off+local) -> Of fp32 (d_out).
template<int EPI, int ALN>
__global__ __launch_bounds__(256) void k_gemm(
    const void* __restrict__ Av, const u16* __restrict__ Bt, int K,
    const float2* __restrict__ stats, const float* __restrict__ lng, const float* __restrict__ lnb,
    const float* __restrict__ biasf,
    const float* __restrict__ resf, const u16* __restrict__ resb,
    u16* __restrict__ O0, u16* __restrict__ O1, u16* __restrict__ O2,
    float* __restrict__ Of,
    int a_off, int o_off)
{
  __shared__ u16 Al[128*LDP];
  __shared__ u16 Bl[128*LDP];
  int tid = threadIdx.x;
  int m0 = blockIdx.y*128, n0 = blockIdx.x*128;
  int w = tid>>6, lane = tid&63, lr = lane&15, lg = lane>>4;
  int wrow = (w>>1)*64, wcol = (w&1)*64;
  f32x4 zero = {0.f,0.f,0.f,0.f};
  f32x4 acc[4][4];
  #pragma unroll
  for (int i=0;i<4;++i)
    #pragma unroll
    for (int j=0;j<4;++j) acc[i][j]=zero;

  for (int kt=0; kt<K; kt+=64){
    #pragma unroll
    for (int it=0; it<4; ++it){
      int vi = tid + it*256;
      int row = vi>>3, cv = (vi&7)*8;
      *(bf16x8*)&Bl[row*LDP+cv] = *(const bf16x8*)(Bt + (size_t)(n0+row)*K + kt + cv);
      if constexpr (ALN==0){
        const u16* A = (const u16*)Av;
        *(bf16x8*)&Al[row*LDP+cv] = *(const bf16x8*)(A + (size_t)(m0+row)*K + kt + cv);
      } else {
        int srow;
        if constexpr (ALN==1){
          int rW = m0+row;
          int q100 = rW/100;
          int n = rW - q100*100;
          int win = a_off + q100;
          srow = ((win>>5)*10 + n/10)*HW_ + (win&31)*10 + (n%10);
        } else {
          srow = a_off + m0 + row;
          srow = srow < 0 ? 0 : (srow > 102399 ? 102399 : srow);
        }
        float2 st = stats[srow];
        float va[8];
        if constexpr (ALN==1){
          const float* A = (const float*)Av;
          float4 f0 = *(const float4*)(A + (size_t)srow*DIM_ + kt + cv);
          float4 f1 = *(const float4*)(A + (size_t)srow*DIM_ + kt + cv + 4);
          va[0]=f0.x; va[1]=f0.y; va[2]=f0.z; va[3]=f0.w;
          va[4]=f1.x; va[5]=f1.y; va[6]=f1.z; va[7]=f1.w;
        } else {
          const u16* A = (const u16*)Av;
          uint4 u = *(const uint4*)(A + (size_t)srow*DIM_ + kt + cv);
          const unsigned* up = (const unsigned*)&u;
          #pragma unroll
          for (int e=0;e<4;++e){ va[2*e]=b2f((u16)(up[e]&0xffff)); va[2*e+1]=b2f((u16)(up[e]>>16)); }
        }
        float4 g0 = *(const float4*)(lng + kt + cv);
        float4 g1 = *(const float4*)(lng + kt + cv + 4);
        float4 c0 = *(const float4*)(lnb + kt + cv);
        float4 c1 = *(const float4*)(lnb + kt + cv + 4);
        float gg[8] = {g0.x,g0.y,g0.z,g0.w,g1.x,g1.y,g1.z,g1.w};
        float cc[8] = {c0.x,c0.y,c0.z,c0.w,c1.x,c1.y,c1.z,c1.w};
        uint4 pk;
        unsigned* pp = (unsigned*)&pk;
        #pragma unroll
        for (int e=0;e<4;++e){
          unsigned lo = f2b((va[2*e]  -st.x)*st.y*gg[2*e]   + cc[2*e]);
          unsigned hi = f2b((va[2*e+1]-st.x)*st.y*gg[2*e+1] + cc[2*e+1]);
          pp[e] = lo | (hi<<16);
        }
        *(uint4*)&Al[row*LDP+cv] = pk;
      }
    }
    __syncthreads();
    #pragma unroll
    for (int k0=0;k0<64;k0+=32){
      bf16x8 af[4], bfr[4];
      #pragma unroll
      for (int i=0;i<4;++i) af[i]  = *(const bf16x8*)&Al[(wrow+i*16+lr)*LDP + k0 + lg*8];
      #pragma unroll
      for (int j=0;j<4;++j) bfr[j] = *(const bf16x8*)&Bl[(wcol+j*16+lr)*LDP + k0 + lg*8];
      #pragma unroll
      for (int i=0;i<4;++i)
        #pragma unroll
        for (int j=0;j<4;++j)
          acc[i][j] = __builtin_amdgcn_mfma_f32_16x16x32_bf16(af[i], bfr[j], acc[i][j],0,0,0);
    }
    __syncthreads();
  }

  #pragma unroll
  for (int i=0;i<4;++i){
    #pragma unroll
    for (int j=0;j<4;++j){
      #pragma unroll
      for (int r=0;r<4;++r){
        int grow = m0 + wrow + i*16 + lg*4 + r;
        int gcol = n0 + wcol + j*16 + lr;
        float v = acc[i][j][r];
        if constexpr (EPI==0){
          v += biasf[gcol];
          int winl = grow/100, n = grow - winl*100;
          int part = gcol>>8, c = gcol&255;
          size_t idx = ((size_t)(winl*8 + (c>>5))*100 + n)*32 + (c&31);
          if (part==0)      O0[idx] = f2b_s(v*SCALE_, 10000.f);
          else if (part==1) O1[idx] = f2b_s(v, 10000.f);
          else              O2[idx] = f2b_s(v, 10000.f);
        } else if constexpr (EPI==1){
          int win = grow/100, n = grow - win*100;
          int wy = win>>5, wxx = win&31;
          int py = n/10, px = n - py*10;
          size_t t = (size_t)((wy*10+py)*HW_ + wxx*10 + px);
          float o = v + biasf[gcol] + resf[t*DIM_ + gcol];
          O0[t*DIM_ + gcol] = f2b_s(o, 30000.f);
        } else if constexpr (EPI==2){
          float o = v + biasf[gcol];
          o = 0.5f*o*(1.0f + erff(o*0.70710678118654752f));
          O0[(size_t)grow*HID_ + gcol] = f2b_s(o, 40000.f);
        } else {
          size_t t = (size_t)(o_off + grow);
          float o = v + biasf[gcol] + b2f(resb[t*DIM_ + gcol]);
          union{float f; unsigned int i;} z; z.f=o;
          if ((z.i & 0x7F800000u) == 0x7F800000u) o = 60000.f;
          Of[t*DIM_ + gcol] = o;
        }
      }
    }
  }
}

// ---------------- window attention: one block per (window, head) ----------------
__global__ __launch_bounds__(256) void k_attn(
    const u16* __restrict__ Q, const u16* __restrict__ Kb, const u16* __restrict__ Vb,
    const float* __restrict__ rpb, u16* __restrict__ Ow, int w_base)
{
  __shared__ float rpb_s[361];
  __shared__ u16 p_lds[112*136];
  __shared__ u16 v_t[32*136];
  int tid = threadIdx.x;
  int wh = blockIdx.x;
  int head = wh & 7, winl = wh >> 3;
  for (int i=tid;i<361;i+=256) rpb_s[i] = rpb[i*8+head];
  for (int i=tid;i<112*136;i+=256) p_lds[i] = 0;
  for (int i=tid;i<32*136;i+=256) v_t[i] = 0;
  __syncthreads();
  const u16* vbase = Vb + (size_t)wh*3200;
  for (int i=tid;i<3200;i+=256){ int m=i>>5, d=i&31; v_t[d*136+m] = vbase[i]; }

  int w = tid>>6, lane = tid&63, lr = lane&15, lg = lane>>4;
  const u16* qbase = Q  + (size_t)wh*3200;
  const u16* kbase = Kb + (size_t)wh*3200;
  f32x4 zero = {0.f,0.f,0.f,0.f};
  bf16x8 aq[2];
  #pragma unroll
  for (int rt=0;rt<2;++rt){
    int qr = w*32 + rt*16 + lr; if (qr>99) qr=99;
    aq[rt] = *(const bf16x8*)(qbase + qr*32 + lg*8);
  }
  f32x4 s[2][7];
  #pragma unroll
  for (int ct=0;ct<7;++ct){
    int kr = ct*16 + lr; if (kr>99) kr=99;
    bf16x8 bk = *(const bf16x8*)(kbase + kr*32 + lg*8);
    s[0][ct] = __builtin_amdgcn_mfma_f32_16x16x32_bf16(aq[0], bk, zero,0,0,0);
    s[1][ct] = __builtin_amdgcn_mfma_f32_16x16x32_bf16(aq[1], bk, zero,0,0,0);
  }
  #pragma unroll
  for (int rt=0;rt<2;++rt){
    #pragma unroll
    for (int ct=0;ct<7;++ct){
      #pragma unroll
      for (int r=0;r<4;++r){
        int n = w*32 + rt*16 + lg*4 + r;
        int m = ct*16 + lr;
        float sv = s[rt][ct][r];
        if (m<100 && n<100)
          sv += rpb_s[(n/10 - m/10 + 9)*19 + (n%10 - m%10 + 9)];
        if (m>=100) sv = NEGINF_;
        s[rt][ct][r] = sv;
      }
    }
  }
  #pragma unroll
  for (int rt=0;rt<2;++rt){
    #pragma unroll
    for (int r=0;r<4;++r){
      float mx = NEGINF_;
      #pragma unroll
      for (int ct=0;ct<7;++ct) mx = fmaxf(mx, s[rt][ct][r]);
      #pragma unroll
      for (int msk=1;msk<16;msk<<=1) mx = fmaxf(mx, __shfl_xor(mx,msk,64));
      float sm = 0.f;
      #pragma unroll
      for (int ct=0;ct<7;++ct){ float p = expf(s[rt][ct][r]-mx); s[rt][ct][r]=p; sm+=p; }
      #pragma unroll
      for (int msk=1;msk<16;msk<<=1) sm += __shfl_xor(sm,msk,64);
      float inv = 1.f/sm;
      int n = w*32 + rt*16 + lg*4 + r;
      if (n < 112){
        #pragma unroll
        for (int ct=0;ct<7;++ct) p_lds[n*136 + ct*16 + lr] = f2b(s[rt][ct][r]*inv);
      }
    }
  }
  __syncthreads();
  f32x4 o[2][2];
  o[0][0]=zero; o[0][1]=zero; o[1][0]=zero; o[1][1]=zero;
  #pragma unroll
  for (int k0=0;k0<128;k0+=32){
    bf16x8 ap[2];
    #pragma unroll
    for (int rt=0;rt<2;++rt){
      int pr = w*32 + rt*16 + lr; if (pr>111) pr=111;
      ap[rt] = *(const bf16x8*)&p_lds[pr*136 + k0 + lg*8];
    }
    #pragma unroll
    for (int dt=0;dt<2;++dt){
      bf16x8 bv = *(const bf16x8*)&v_t[(dt*16+lr)*136 + k0 + lg*8];
      o[0][dt] = __builtin_amdgcn_mfma_f32_16x16x32_bf16(ap[0], bv, o[0][dt],0,0,0);
      o[1][dt] = __builtin_amdgcn_mfma_f32_16x16x32_bf16(ap[1], bv, o[1][dt],0,0,0);
    }
  }
  int win_g = w_base + winl;
  #pragma unroll
  for (int rt=0;rt<2;++rt){
    #pragma unroll
    for (int dt=0;dt<2;++dt){
      #pragma unroll
      for (int r=0;r<4;++r){
        int n = w*32 + rt*16 + lg*4 + r;
        if (n<100)
          Ow[((size_t)(win_g*100+n))*DIM_ + head*32 + dt*16 + lr] = f2b_s(o[rt][dt][r], 20000.f);
      }
    }
  }
}

// ---------------- banded 3x3 depthwise conv + gelu ----------------
// fband: [BANDH+2 lines, 1024] bf16 = scanlines [y0-1, y0+BANDH+1). gband: [BANDH*320,1024].
__global__ __launch_bounds__(256) void k_dwconv(const u16* __restrict__ f,
    const float* __restrict__ wgt, const float* __restrict__ bias, u16* __restrict__ g, int y0)
{
  int gid = blockIdx.x*256 + threadIdx.x;
  int p = gid >> 7;
  int cg = (gid & 127) << 3;
  int py = p/HW_, x = p - py*HW_;
  int y = y0 + py;
  float acc[8];
  #pragma unroll
  for (int c=0;c<8;++c) acc[c] = bias[cg+c];
  for (int ky=-1;ky<=1;++ky){
    int yy = y+ky; if (yy<0 || yy>=HW_) continue;
    int lrow = py + ky + 1;
    for (int kx=-1;kx<=1;++kx){
      int xx = x+kx; if (xx<0 || xx>=HW_) continue;
      uint4 u = *(const uint4*)(f + ((size_t)(lrow*HW_+xx))*HID_ + cg);
      int kk = (ky+1)*3 + (kx+1);
      float fv[8] = { b2f((u16)(u.x&0xffff)), b2f((u16)(u.x>>16)),
                      b2f((u16)(u.y&0xffff)), b2f((u16)(u.y>>16)),
                      b2f((u16)(u.z&0xffff)), b2f((u16)(u.z>>16)),
                      b2f((u16)(u.w&0xffff)), b2f((u16)(u.w>>16)) };
      #pragma unroll
      for (int c=0;c<8;++c) acc[c] += fv[c]*wgt[(cg+c)*9 + kk];
    }
  }
  u16 ov[8];
  #pragma unroll
  for (int c=0;c<8;++c){
    float v = acc[c];
    v = 0.5f*v*(1.0f + erff(v*0.70710678118654752f));
    ov[c] = f2b_s(v, 50000.f);
  }
  uint4 pack;
  pack.x = (unsigned)ov[0] | ((unsigned)ov[1]<<16);
  pack.y = (unsigned)ov[2] | ((unsigned)ov[3]<<16);
  pack.z = (unsigned)ov[4] | ((unsigned)ov[5]<<16);
  pack.w = (unsigned)ov[6] | ((unsigned)ov[7]<<16);
  *(uint4*)(g + ((size_t)p)*HID_ + cg) = pack;
}

extern "C" void kernel_launch(void* const* d_in, const int* in_sizes, int n_in,
                              void* d_out, int out_size, void* d_ws, size_t ws_size,
                              hipStream_t stream)
{
  (void)in_sizes; (void)n_in; (void)out_size; (void)ws_size;
  const float* x     = (const float*)d_in[0];
  const float* n1g   = (const float*)d_in[1];
  const float* n1b   = (const float*)d_in[2];
  const float* wq    = (const float*)d_in[3];
  const float* bq    = (const float*)d_in[4];
  const float* wkv   = (const float*)d_in[5];
  const float* bkv   = (const float*)d_in[6];
  const float* rpb   = (const float*)d_in[7];
  const float* projw = (const float*)d_in[8];
  const float* projb = (const float*)d_in[9];
  const float* n2g   = (const float*)d_in[10];
  const float* n2b   = (const float*)d_in[11];
  const float* l1w   = (const float*)d_in[12];
  const float* l1b   = (const float*)d_in[13];
  const float* dww   = (const float*)d_in[14];
  const float* dwb   = (const float*)d_in[15];
  const float* l2w   = (const float*)d_in[16];
  const float* l2b   = (const float*)d_in[17];

  char* ws = (char*)d_ws;                       // ws_size = 400 MiB (measured via harness poison fill)
  // tables (3.2 MB)
  u16*   WqkvT   = (u16*)(ws + 0);              //   393,216 B
  u16*   projT   = (u16*)(ws + 393216);         //   131,072
  u16*   l1T     = (u16*)(ws + 524288);         //   524,288
  u16*   l2T     = (u16*)(ws + 1048576);        //   524,288
  float* qkvbias = (float*)(ws + 1572864);      //     3,072
  float2* stats1 = (float2*)(ws + 1576960);     //   819,200
  float2* stats2 = (float2*)(ws + 2396160);     //   819,200
  u16*   x1      = (u16*)(ws + 3276800);        // 52,428,800 -> 55,705,600
  char*  BR      = ws + 55705600;
  u16* Qb    = (u16*)(BR + 0);                  // 52,428,800 (full, 1024 windows)
  u16* Kbuf  = (u16*)(BR + 52428800);           // 52,428,800
  u16* Vbuf  = (u16*)(BR + 104857600);          // 52,428,800 -> total 212,992,000 (<419 MB)
  u16* fband = (u16*)(BR + 0);                  // 106,168,320 (162*320*1024*2)
  u16* gband = (u16*)(BR + 106168320);          // 104,857,600 (160*320*1024*2) -> 266,731,520
  u16* owin  = (u16*)d_out;                     // bf16 scratch inside fp32 out buffer
  float* outp = (float*)d_out;

  // weight transposes (fp32 -> bf16) + bias table
  k_transpose<<<256, 256, 0, stream>>>(wq,   WqkvT,          256, 256);
  k_transpose<<<512, 256, 0, stream>>>(wkv,  WqkvT + 65536,  256, 512);
  k_transpose<<<256, 256, 0, stream>>>(projw, projT,         256, 256);
  k_transpose<<<1024,256, 0, stream>>>(l1w,  l1T,            256, 1024);
  k_transpose<<<1024,256, 0, stream>>>(l2w,  l2T,            1024, 256);
  k_qkvbias<<<3, 256, 0, stream>>>(bq, bkv, qkvbias);

  // LN1 stats
  k_stats_f32<<<25600, 256, 0, stream>>>(x, stats1);
  // QKV projection (full, LN+window-gather fused into A staging)
  k_gemm<0,1><<<dim3(6,800), 256, 0, stream>>>(x, WqkvT, 256,
      stats1, n1g, n1b, qkvbias, nullptr, nullptr, Qb, Kbuf, Vbuf, nullptr, 0, 0);
  // window attention (all 8192 window-head blocks)
  k_attn<<<8192, 256, 0, stream>>>(Qb, Kbuf, Vbuf, rpb, owin, 0);
  // proj + residual(x fp32) + window reverse -> x1 bf16
  k_gemm<1,0><<<dim3(2,800), 256, 0, stream>>>(owin, projT, 256,
      nullptr, nullptr, nullptr, projb, x, nullptr, x1, nullptr, nullptr, nullptr, 0, 0);
  // LN2 stats (from x1 bf16)
  k_stats_bf16<<<25600, 256, 0, stream>>>(x1, stats2);
  // banded LeFF: 2 bands of 160 scanlines
  for (int b=0; b<2; ++b){
    int y0 = 160*b;
    k_gemm<2,2><<<dim3(8,405), 256, 0, stream>>>(x1, l1T, 256,
        stats2, n2g, n2b, l1b, nullptr, nullptr, fband, nullptr, nullptr, nullptr,
        (y0-1)*HW_, 0);
    k_dwconv<<<25600, 256, 0, stream>>>(fband, dww, dwb, gband, y0);
    k_gemm<3,0><<<dim3(2,400), 256, 0, stream>>>(gband, l2T, 1024,
        nullptr, nullptr, nullptr, l2b, nullptr, x1, nullptr, nullptr, nullptr, outp,
        0, y0*HW_);
  }
}

// Round 7
// 962.314 us; speedup vs baseline: 4.1232x; 2.5437x over previous
//
#include <hip/hip_runtime.h>
#include <hip/hip_bf16.h>

typedef unsigned short u16;
typedef __attribute__((ext_vector_type(8))) __bf16 bf16x8;
typedef __attribute__((ext_vector_type(4))) float f32x4;

#define HW_ 320
#define DIM_ 256
#define HID_ 1024
#define SCALE_ 0.1767766952966369f
#define LDP 72
#define NEGINF_ -30000.0f

__device__ __forceinline__ float b2f(u16 u){
  union{unsigned int i; float f;} z; z.i=((unsigned int)u)<<16; return z.f;
}
__device__ __forceinline__ u16 f2b(float f){
  union{float f; unsigned int i;} z; z.f=f;
  return (u16)((z.i + 0x7fffu + ((z.i>>16)&1u))>>16);
}
__device__ __forceinline__ u16 f2b_s(float f, float sub){
  union{float f; unsigned int i;} z; z.f=f;
  if ((z.i & 0x7F800000u) == 0x7F800000u) z.f = sub;
  return (u16)((z.i + 0x7fffu + ((z.i>>16)&1u))>>16);
}
// fast gelu: tanh form via hardware exp (|err| ~1e-3 << 0.109 threshold)
__device__ __forceinline__ float gelu_f(float v){
  float u = 0.7978845608028654f*(v + 0.044715f*v*v*v);
  float e = __expf(2.f*u);
  float t = 1.f - 2.f/(e+1.f);
  return 0.5f*v*(1.f+t);
}

// ---------------- prep: fp32 weight -> bf16 transposed ----------------
__global__ void k_transpose(const float* __restrict__ src, u16* __restrict__ dst, int K, int N){
  int i = blockIdx.x*256 + threadIdx.x;
  if (i < K*N){ int k = i / N, n = i - k*N; dst[(size_t)n*K + k] = f2b(src[i]); }
}
// dw weights [1024][9] fp32 -> [9][1024] bf16
__global__ void k_transpose_dw(const float* __restrict__ src, u16* __restrict__ dst){
  int i = blockIdx.x*256 + threadIdx.x;
  if (i < 9216){ int ch = i / 9, kk = i - ch*9; dst[kk*1024 + ch] = f2b(src[i]); }
}
__global__ void k_qkvbias(const float* __restrict__ bq, const float* __restrict__ bkv, float* __restrict__ dst){
  int i = blockIdx.x*256 + threadIdx.x;
  if (i < 768) dst[i] = (i<256) ? bq[i] : bkv[i-256];
}

// ---------------- per-row LN stats ----------------
__global__ __launch_bounds__(256) void k_stats_f32(const float* __restrict__ x, float2* __restrict__ st){
  int tid = threadIdx.x, lane = tid & 63;
  int t = blockIdx.x*4 + (tid>>6);
  float4 v = *(const float4*)(x + (size_t)t*DIM_ + lane*4);
  float s  = v.x+v.y+v.z+v.w;
  float ss = v.x*v.x+v.y*v.y+v.z*v.z+v.w*v.w;
  for (int m=1;m<64;m<<=1){ s += __shfl_xor(s,m,64); ss += __shfl_xor(ss,m,64); }
  float mean = s*(1.0f/DIM_);
  float var  = ss*(1.0f/DIM_) - mean*mean;
  if (var < 0.f) var = 0.f;
  if (lane==0) st[t] = make_float2(mean, rsqrtf(var + 1e-5f));
}
__global__ __launch_bounds__(256) void k_stats_bf16(const u16* __restrict__ x, float2* __restrict__ st){
  int tid = threadIdx.x, lane = tid & 63;
  int t = blockIdx.x*4 + (tid>>6);
  uint2 u = *(const uint2*)(x + (size_t)t*DIM_ + lane*4);
  float v0=b2f((u16)(u.x&0xffff)), v1=b2f((u16)(u.x>>16));
  float v2=b2f((u16)(u.y&0xffff)), v3=b2f((u16)(u.y>>16));
  float s  = v0+v1+v2+v3;
  float ss = v0*v0+v1*v1+v2*v2+v3*v3;
  for (int m=1;m<64;m<<=1){ s += __shfl_xor(s,m,64); ss += __shfl_xor(ss,m,64); }
  float mean = s*(1.0f/DIM_);
  float var  = ss*(1.0f/DIM_) - mean*mean;
  if (var < 0.f) var = 0.f;
  if (lane==0) st[t] = make_float2(mean, rsqrtf(var + 1e-5f));
}

// ---------------- generic MFMA GEMM: C = A[M,K] * Bt[N,K]^T ----------------
// ALN 0: A bf16 rows (owin / gband).
// ALN 1: A = x (fp32), LN inline + window-gather; a_off = window base.
// ALN 2: A = x1 (bf16), LN inline, srow = clamp(a_off + local).
// EPI 0: qkv scatter -> Q/K/V bf16 (biasf fp32[768]).
// EPI 1: + biasf + resf(x fp32) + window-reverse -> O0 = x1 bf16 (global rows).
// EPI 2: + biasf, gelu -> O0 = fband bf16 [local,1024].
// EPI 3: + biasf + resb(x1 bf16, rows o_off+local) -> Of fp32 (d_out).
template<int EPI, int ALN>
__global__ __launch_bounds__(256) void k_gemm(
    const void* __restrict__ Av, const u16* __restrict__ Bt, int K,
    const float2* __restrict__ stats, const float* __restrict__ lng, const float* __restrict__ lnb,
    const float* __restrict__ biasf,
    const float* __restrict__ resf, const u16* __restrict__ resb,
    u16* __restrict__ O0, u16* __restrict__ O1, u16* __restrict__ O2,
    float* __restrict__ Of,
    int a_off, int o_off)
{
  __shared__ u16 Al[128*LDP];
  __shared__ u16 Bl[128*LDP];
  int tid = threadIdx.x;
  int m0 = blockIdx.y*128, n0 = blockIdx.x*128;
  int w = tid>>6, lane = tid&63, lr = lane&15, lg = lane>>4;
  int wrow = (w>>1)*64, wcol = (w&1)*64;
  f32x4 zero = {0.f,0.f,0.f,0.f};
  f32x4 acc[4][4];
  #pragma unroll
  for (int i=0;i<4;++i)
    #pragma unroll
    for (int j=0;j<4;++j) acc[i][j]=zero;

  for (int kt=0; kt<K; kt+=64){
    #pragma unroll
    for (int it=0; it<4; ++it){
      int vi = tid + it*256;
      int row = vi>>3, cv = (vi&7)*8;
      *(bf16x8*)&Bl[row*LDP+cv] = *(const bf16x8*)(Bt + (size_t)(n0+row)*K + kt + cv);
      if constexpr (ALN==0){
        const u16* A = (const u16*)Av;
        *(bf16x8*)&Al[row*LDP+cv] = *(const bf16x8*)(A + (size_t)(m0+row)*K + kt + cv);
      } else {
        int srow;
        if constexpr (ALN==1){
          int rW = m0+row;
          int q100 = rW/100;
          int n = rW - q100*100;
          int win = a_off + q100;
          srow = ((win>>5)*10 + n/10)*HW_ + (win&31)*10 + (n%10);
        } else {
          srow = a_off + m0 + row;
          srow = srow < 0 ? 0 : (srow > 102399 ? 102399 : srow);
        }
        float2 st = stats[srow];
        float va[8];
        if constexpr (ALN==1){
          const float* A = (const float*)Av;
          float4 f0 = *(const float4*)(A + (size_t)srow*DIM_ + kt + cv);
          float4 f1 = *(const float4*)(A + (size_t)srow*DIM_ + kt + cv + 4);
          va[0]=f0.x; va[1]=f0.y; va[2]=f0.z; va[3]=f0.w;
          va[4]=f1.x; va[5]=f1.y; va[6]=f1.z; va[7]=f1.w;
        } else {
          const u16* A = (const u16*)Av;
          uint4 u = *(const uint4*)(A + (size_t)srow*DIM_ + kt + cv);
          const unsigned* up = (const unsigned*)&u;
          #pragma unroll
          for (int e=0;e<4;++e){ va[2*e]=b2f((u16)(up[e]&0xffff)); va[2*e+1]=b2f((u16)(up[e]>>16)); }
        }
        float4 g0 = *(const float4*)(lng + kt + cv);
        float4 g1 = *(const float4*)(lng + kt + cv + 4);
        float4 c0 = *(const float4*)(lnb + kt + cv);
        float4 c1 = *(const float4*)(lnb + kt + cv + 4);
        float gg[8] = {g0.x,g0.y,g0.z,g0.w,g1.x,g1.y,g1.z,g1.w};
        float cc[8] = {c0.x,c0.y,c0.z,c0.w,c1.x,c1.y,c1.z,c1.w};
        uint4 pk;
        unsigned* pp = (unsigned*)&pk;
        #pragma unroll
        for (int e=0;e<4;++e){
          unsigned lo = f2b((va[2*e]  -st.x)*st.y*gg[2*e]   + cc[2*e]);
          unsigned hi = f2b((va[2*e+1]-st.x)*st.y*gg[2*e+1] + cc[2*e+1]);
          pp[e] = lo | (hi<<16);
        }
        *(uint4*)&Al[row*LDP+cv] = pk;
      }
    }
    __syncthreads();
    #pragma unroll
    for (int k0=0;k0<64;k0+=32){
      bf16x8 af[4], bfr[4];
      #pragma unroll
      for (int i=0;i<4;++i) af[i]  = *(const bf16x8*)&Al[(wrow+i*16+lr)*LDP + k0 + lg*8];
      #pragma unroll
      for (int j=0;j<4;++j) bfr[j] = *(const bf16x8*)&Bl[(wcol+j*16+lr)*LDP + k0 + lg*8];
      #pragma unroll
      for (int i=0;i<4;++i)
        #pragma unroll
        for (int j=0;j<4;++j)
          acc[i][j] = __builtin_amdgcn_mfma_f32_16x16x32_bf16(af[i], bfr[j], acc[i][j],0,0,0);
    }
    __syncthreads();
  }

  #pragma unroll
  for (int i=0;i<4;++i){
    #pragma unroll
    for (int j=0;j<4;++j){
      #pragma unroll
      for (int r=0;r<4;++r){
        int grow = m0 + wrow + i*16 + lg*4 + r;
        int gcol = n0 + wcol + j*16 + lr;
        float v = acc[i][j][r];
        if constexpr (EPI==0){
          v += biasf[gcol];
          int winl = grow/100, n = grow - winl*100;
          int part = gcol>>8, c = gcol&255;
          size_t idx = ((size_t)(winl*8 + (c>>5))*100 + n)*32 + (c&31);
          if (part==0)      O0[idx] = f2b_s(v*SCALE_, 10000.f);
          else if (part==1) O1[idx] = f2b_s(v, 10000.f);
          else              O2[idx] = f2b_s(v, 10000.f);
        } else if constexpr (EPI==1){
          int win = grow/100, n = grow - win*100;
          int wy = win>>5, wxx = win&31;
          int py = n/10, px = n - py*10;
          size_t t = (size_t)((wy*10+py)*HW_ + wxx*10 + px);
          float o = v + biasf[gcol] + resf[t*DIM_ + gcol];
          O0[t*DIM_ + gcol] = f2b_s(o, 30000.f);
        } else if constexpr (EPI==2){
          float o = gelu_f(v + biasf[gcol]);
          O0[(size_t)grow*HID_ + gcol] = f2b_s(o, 40000.f);
        } else {
          size_t t = (size_t)(o_off + grow);
          float o = v + biasf[gcol] + b2f(resb[t*DIM_ + gcol]);
          union{float f; unsigned int i;} z; z.f=o;
          if ((z.i & 0x7F800000u) == 0x7F800000u) o = 60000.f;
          Of[t*DIM_ + gcol] = o;
        }
      }
    }
  }
}

// ---------------- window attention: one block per (window, head) ----------------
__global__ __launch_bounds__(256) void k_attn(
    const u16* __restrict__ Q, const u16* __restrict__ Kb, const u16* __restrict__ Vb,
    const float* __restrict__ rpb, u16* __restrict__ Ow, int w_base)
{
  __shared__ float rpb_s[361];
  __shared__ u16 p_lds[112*136];
  __shared__ u16 v_t[32*136];
  int tid = threadIdx.x;
  int wh = blockIdx.x;
  int head = wh & 7, winl = wh >> 3;
  for (int i=tid;i<361;i+=256) rpb_s[i] = rpb[i*8+head];
  for (int i=tid;i<112*136;i+=256) p_lds[i] = 0;
  for (int i=tid;i<32*136;i+=256) v_t[i] = 0;
  __syncthreads();
  const u16* vbase = Vb + (size_t)wh*3200;
  for (int i=tid;i<3200;i+=256){ int m=i>>5, d=i&31; v_t[d*136+m] = vbase[i]; }

  int w = tid>>6, lane = tid&63, lr = lane&15, lg = lane>>4;
  const u16* qbase = Q  + (size_t)wh*3200;
  const u16* kbase = Kb + (size_t)wh*3200;
  f32x4 zero = {0.f,0.f,0.f,0.f};
  bf16x8 aq[2];
  #pragma unroll
  for (int rt=0;rt<2;++rt){
    int qr = w*32 + rt*16 + lr; if (qr>99) qr=99;
    aq[rt] = *(const bf16x8*)(qbase + qr*32 + lg*8);
  }
  f32x4 s[2][7];
  #pragma unroll
  for (int ct=0;ct<7;++ct){
    int kr = ct*16 + lr; if (kr>99) kr=99;
    bf16x8 bk = *(const bf16x8*)(kbase + kr*32 + lg*8);
    s[0][ct] = __builtin_amdgcn_mfma_f32_16x16x32_bf16(aq[0], bk, zero,0,0,0);
    s[1][ct] = __builtin_amdgcn_mfma_f32_16x16x32_bf16(aq[1], bk, zero,0,0,0);
  }
  #pragma unroll
  for (int rt=0;rt<2;++rt){
    #pragma unroll
    for (int ct=0;ct<7;++ct){
      #pragma unroll
      for (int r=0;r<4;++r){
        int n = w*32 + rt*16 + lg*4 + r;
        int m = ct*16 + lr;
        float sv = s[rt][ct][r];
        if (m<100 && n<100)
          sv += rpb_s[(n/10 - m/10 + 9)*19 + (n%10 - m%10 + 9)];
        if (m>=100) sv = NEGINF_;
        s[rt][ct][r] = sv;
      }
    }
  }
  #pragma unroll
  for (int rt=0;rt<2;++rt){
    #pragma unroll
    for (int r=0;r<4;++r){
      float mx = NEGINF_;
      #pragma unroll
      for (int ct=0;ct<7;++ct) mx = fmaxf(mx, s[rt][ct][r]);
      #pragma unroll
      for (int msk=1;msk<16;msk<<=1) mx = fmaxf(mx, __shfl_xor(mx,msk,64));
      float sm = 0.f;
      #pragma unroll
      for (int ct=0;ct<7;++ct){ float p = expf(s[rt][ct][r]-mx); s[rt][ct][r]=p; sm+=p; }
      #pragma unroll
      for (int msk=1;msk<16;msk<<=1) sm += __shfl_xor(sm,msk,64);
      float inv = 1.f/sm;
      int n = w*32 + rt*16 + lg*4 + r;
      if (n < 112){
        #pragma unroll
        for (int ct=0;ct<7;++ct) p_lds[n*136 + ct*16 + lr] = f2b(s[rt][ct][r]*inv);
      }
    }
  }
  __syncthreads();
  f32x4 o[2][2];
  o[0][0]=zero; o[0][1]=zero; o[1][0]=zero; o[1][1]=zero;
  #pragma unroll
  for (int k0=0;k0<128;k0+=32){
    bf16x8 ap[2];
    #pragma unroll
    for (int rt=0;rt<2;++rt){
      int pr = w*32 + rt*16 + lr; if (pr>111) pr=111;
      ap[rt] = *(const bf16x8*)&p_lds[pr*136 + k0 + lg*8];
    }
    #pragma unroll
    for (int dt=0;dt<2;++dt){
      bf16x8 bv = *(const bf16x8*)&v_t[(dt*16+lr)*136 + k0 + lg*8];
      o[0][dt] = __builtin_amdgcn_mfma_f32_16x16x32_bf16(ap[0], bv, o[0][dt],0,0,0);
      o[1][dt] = __builtin_amdgcn_mfma_f32_16x16x32_bf16(ap[1], bv, o[1][dt],0,0,0);
    }
  }
  int win_g = w_base + winl;
  #pragma unroll
  for (int rt=0;rt<2;++rt){
    #pragma unroll
    for (int dt=0;dt<2;++dt){
      #pragma unroll
      for (int r=0;r<4;++r){
        int n = w*32 + rt*16 + lg*4 + r;
        if (n<100)
          Ow[((size_t)(win_g*100+n))*DIM_ + head*32 + dt*16 + lr] = f2b_s(o[rt][dt][r], 20000.f);
      }
    }
  }
}

// ---------------- banded 3x3 depthwise conv + gelu, v2 ----------------
// Thread owns (x, 8-ch group); slides down YT rows. Weights [9][1024] bf16,
// loaded coalesced once. fband local rows: 0 = global y0-1.
#define YT_ 10
__global__ __launch_bounds__(256) void k_dwconv2(const u16* __restrict__ f,
    const u16* __restrict__ wT, const float* __restrict__ bias,
    u16* __restrict__ g, int y0)
{
  int tid = threadIdx.x;
  int bid = blockIdx.x;
  int xt = bid % 160, yt = bid / 160;
  int x  = xt*2 + (tid>>7);
  int cg = (tid&127)<<3;
  int yl0 = yt*YT_;

  float w[9][8];
  #pragma unroll
  for (int kk=0;kk<9;++kk){
    uint4 u = *(const uint4*)(wT + kk*1024 + cg);
    const unsigned* up=(const unsigned*)&u;
    #pragma unroll
    for(int e=0;e<4;++e){ w[kk][2*e]=b2f((u16)(up[e]&0xffff)); w[kk][2*e+1]=b2f((u16)(up[e]>>16)); }
  }
  float bs[8];
  {
    float4 b0 = *(const float4*)(bias+cg);
    float4 b1 = *(const float4*)(bias+cg+4);
    bs[0]=b0.x;bs[1]=b0.y;bs[2]=b0.z;bs[3]=b0.w;bs[4]=b1.x;bs[5]=b1.y;bs[6]=b1.z;bs[7]=b1.w;
  }
  uint4 zq = make_uint4(0,0,0,0);
  auto ld = [&](int ytap, int xx)->uint4{
    int yy = y0 + ytap;
    if (xx<0 || xx>=HW_ || yy<0 || yy>=HW_) return zq;
    return *(const uint4*)(f + ((size_t)((ytap+1-yl0+yl0)*0 + (ytap+1))*HW_ + (size_t)0)*0 + ((size_t)((ytap+1)*HW_+xx))*HID_ + cg);
  };
  uint4 a00=ld(yl0-1,x-1), a01=ld(yl0-1,x), a02=ld(yl0-1,x+1);
  uint4 a10=ld(yl0  ,x-1), a11=ld(yl0  ,x), a12=ld(yl0  ,x+1);
  #pragma unroll
  for (int r=0;r<YT_;++r){
    int yl = yl0 + r;
    uint4 a20=ld(yl+1,x-1), a21=ld(yl+1,x), a22=ld(yl+1,x+1);
    float acc[8];
    #pragma unroll
    for (int c=0;c<8;++c) acc[c]=bs[c];
    auto fma8 = [&](const uint4& a, const float (&wk)[8]){
      const unsigned* up=(const unsigned*)&a;
      #pragma unroll
      for(int e=0;e<4;++e){
        acc[2*e]   += b2f((u16)(up[e]&0xffff)) * wk[2*e];
        acc[2*e+1] += b2f((u16)(up[e]>>16))    * wk[2*e+1];
      }
    };
    fma8(a00,w[0]); fma8(a01,w[1]); fma8(a02,w[2]);
    fma8(a10,w[3]); fma8(a11,w[4]); fma8(a12,w[5]);
    fma8(a20,w[6]); fma8(a21,w[7]); fma8(a22,w[8]);
    u16 ov[8];
    #pragma unroll
    for (int c=0;c<8;++c) ov[c] = f2b_s(gelu_f(acc[c]), 50000.f);
    uint4 pack;
    pack.x = (unsigned)ov[0] | ((unsigned)ov[1]<<16);
    pack.y = (unsigned)ov[2] | ((unsigned)ov[3]<<16);
    pack.z = (unsigned)ov[4] | ((unsigned)ov[5]<<16);
    pack.w = (unsigned)ov[6] | ((unsigned)ov[7]<<16);
    *(uint4*)(g + ((size_t)(yl*HW_+x))*HID_ + cg) = pack;
    a00=a10;a01=a11;a02=a12; a10=a20;a11=a21;a12=a22;
  }
}

extern "C" void kernel_launch(void* const* d_in, const int* in_sizes, int n_in,
                              void* d_out, int out_size, void* d_ws, size_t ws_size,
                              hipStream_t stream)
{
  (void)in_sizes; (void)n_in; (void)out_size; (void)ws_size;
  const float* x     = (const float*)d_in[0];
  const float* n1g   = (const float*)d_in[1];
  const float* n1b   = (const float*)d_in[2];
  const float* wq    = (const float*)d_in[3];
  const float* bq    = (const float*)d_in[4];
  const float* wkv   = (const float*)d_in[5];
  const float* bkv   = (const float*)d_in[6];
  const float* rpb   = (const float*)d_in[7];
  const float* projw = (const float*)d_in[8];
  const float* projb = (const float*)d_in[9];
  const float* n2g   = (const float*)d_in[10];
  const float* n2b   = (const float*)d_in[11];
  const float* l1w   = (const float*)d_in[12];
  const float* l1b   = (const float*)d_in[13];
  const float* dww   = (const float*)d_in[14];
  const float* dwb   = (const float*)d_in[15];
  const float* l2w   = (const float*)d_in[16];
  const float* l2b   = (const float*)d_in[17];

  char* ws = (char*)d_ws;                       // ws_size = 400 MiB (measured via harness poison fill)
  u16*   WqkvT   = (u16*)(ws + 0);              //   393,216 B
  u16*   projT   = (u16*)(ws + 393216);         //   131,072
  u16*   l1T     = (u16*)(ws + 524288);         //   524,288
  u16*   l2T     = (u16*)(ws + 1048576);        //   524,288
  float* qkvbias = (float*)(ws + 1572864);      //     3,072
  float2* stats1 = (float2*)(ws + 1576960);     //   819,200
  float2* stats2 = (float2*)(ws + 2396160);     //   819,200
  u16*   dwT     = (u16*)(ws + 3215360);        //    18,432 (ends 3,233,792)
  u16*   x1      = (u16*)(ws + 3276800);        // 52,428,800 -> 55,705,600
  char*  BR      = ws + 55705600;
  u16* Qb    = (u16*)(BR + 0);                  // 52,428,800 (full, 1024 windows)
  u16* Kbuf  = (u16*)(BR + 52428800);
  u16* Vbuf  = (u16*)(BR + 104857600);          // -> total 212,992,000 (< ~419 MB)
  u16* fband = (u16*)(BR + 0);                  // 106,168,320 (162*320*1024*2)
  u16* gband = (u16*)(BR + 106168320);          // 104,857,600 (160*320*1024*2)
  u16* owin  = (u16*)d_out;
  float* outp = (float*)d_out;

  k_transpose<<<256, 256, 0, stream>>>(wq,   WqkvT,          256, 256);
  k_transpose<<<512, 256, 0, stream>>>(wkv,  WqkvT + 65536,  256, 512);
  k_transpose<<<256, 256, 0, stream>>>(projw, projT,         256, 256);
  k_transpose<<<1024,256, 0, stream>>>(l1w,  l1T,            256, 1024);
  k_transpose<<<1024,256, 0, stream>>>(l2w,  l2T,            1024, 256);
  k_transpose_dw<<<36, 256, 0, stream>>>(dww, dwT);
  k_qkvbias<<<3, 256, 0, stream>>>(bq, bkv, qkvbias);

  // LN1 stats
  k_stats_f32<<<25600, 256, 0, stream>>>(x, stats1);
  // QKV projection (LN + window-gather fused into A staging)
  k_gemm<0,1><<<dim3(6,800), 256, 0, stream>>>(x, WqkvT, 256,
      stats1, n1g, n1b, qkvbias, nullptr, nullptr, Qb, Kbuf, Vbuf, nullptr, 0, 0);
  // window attention
  k_attn<<<8192, 256, 0, stream>>>(Qb, Kbuf, Vbuf, rpb, owin, 0);
  // proj + residual(x fp32) + window reverse -> x1 bf16
  k_gemm<1,0><<<dim3(2,800), 256, 0, stream>>>(owin, projT, 256,
      nullptr, nullptr, nullptr, projb, x, nullptr, x1, nullptr, nullptr, nullptr, 0, 0);
  // LN2 stats
  k_stats_bf16<<<25600, 256, 0, stream>>>(x1, stats2);
  // banded LeFF: 2 bands of 160 scanlines
  for (int b=0; b<2; ++b){
    int y0 = 160*b;
    k_gemm<2,2><<<dim3(8,405), 256, 0, stream>>>(x1, l1T, 256,
        stats2, n2g, n2b, l1b, nullptr, nullptr, fband, nullptr, nullptr, nullptr,
        (y0-1)*HW_, 0);
    k_dwconv2<<<2560, 256, 0, stream>>>(fband, dwT, dwb, gband, y0 /* note: ld uses band-local ytap; y0 only for image-edge test */);
    k_gemm<3,0><<<dim3(2,400), 256, 0, stream>>>(gband, l2T, 1024,
        nullptr, nullptr, nullptr, l2b, nullptr, x1, nullptr, nullptr, nullptr, outp,
        0, y0*HW_);
  }
}

// Round 8
// 898.867 us; speedup vs baseline: 4.4143x; 1.0706x over previous
//
#include <hip/hip_runtime.h>
#include <hip/hip_bf16.h>

typedef unsigned short u16;
typedef __attribute__((ext_vector_type(8))) __bf16 bf16x8;
typedef __attribute__((ext_vector_type(4))) float f32x4;

#define HW_ 320
#define DIM_ 256
#define HID_ 1024
#define SCALE_ 0.1767766952966369f
#define LDP 72
#define NEGINF_ -30000.0f

__device__ __forceinline__ float b2f(u16 u){
  union{unsigned int i; float f;} z; z.i=((unsigned int)u)<<16; return z.f;
}
__device__ __forceinline__ u16 f2b(float f){
  union{float f; unsigned int i;} z; z.f=f;
  return (u16)((z.i + 0x7fffu + ((z.i>>16)&1u))>>16);
}
__device__ __forceinline__ u16 f2b_s(float f, float sub){
  union{float f; unsigned int i;} z; z.f=f;
  if ((z.i & 0x7F800000u) == 0x7F800000u) z.f = sub;
  return (u16)((z.i + 0x7fffu + ((z.i>>16)&1u))>>16);
}
// fast gelu: tanh form via hardware exp (|err| ~1e-3 << 0.109 threshold)
__device__ __forceinline__ float gelu_f(float v){
  float u = 0.7978845608028654f*(v + 0.044715f*v*v*v);
  float e = __expf(2.f*u);
  float t = 1.f - 2.f/(e+1.f);
  return 0.5f*v*(1.f+t);
}

// ---------------- prep: fp32 weight -> bf16 transposed ----------------
__global__ void k_transpose(const float* __restrict__ src, u16* __restrict__ dst, int K, int N){
  int i = blockIdx.x*256 + threadIdx.x;
  if (i < K*N){ int k = i / N, n = i - k*N; dst[(size_t)n*K + k] = f2b(src[i]); }
}
// dw weights [1024][9] fp32 -> [9][1024] bf16
__global__ void k_transpose_dw(const float* __restrict__ src, u16* __restrict__ dst){
  int i = blockIdx.x*256 + threadIdx.x;
  if (i < 9216){ int ch = i / 9, kk = i - ch*9; dst[kk*1024 + ch] = f2b(src[i]); }
}
__global__ void k_qkvbias(const float* __restrict__ bq, const float* __restrict__ bkv, float* __restrict__ dst){
  int i = blockIdx.x*256 + threadIdx.x;
  if (i < 768) dst[i] = (i<256) ? bq[i] : bkv[i-256];
}

// ---------------- per-row LN stats ----------------
__global__ __launch_bounds__(256) void k_stats_f32(const float* __restrict__ x, float2* __restrict__ st){
  int tid = threadIdx.x, lane = tid & 63;
  int t = blockIdx.x*4 + (tid>>6);
  float4 v = *(const float4*)(x + (size_t)t*DIM_ + lane*4);
  float s  = v.x+v.y+v.z+v.w;
  float ss = v.x*v.x+v.y*v.y+v.z*v.z+v.w*v.w;
  for (int m=1;m<64;m<<=1){ s += __shfl_xor(s,m,64); ss += __shfl_xor(ss,m,64); }
  float mean = s*(1.0f/DIM_);
  float var  = ss*(1.0f/DIM_) - mean*mean;
  if (var < 0.f) var = 0.f;
  if (lane==0) st[t] = make_float2(mean, rsqrtf(var + 1e-5f));
}
__global__ __launch_bounds__(256) void k_stats_bf16(const u16* __restrict__ x, float2* __restrict__ st){
  int tid = threadIdx.x, lane = tid & 63;
  int t = blockIdx.x*4 + (tid>>6);
  uint2 u = *(const uint2*)(x + (size_t)t*DIM_ + lane*4);
  float v0=b2f((u16)(u.x&0xffff)), v1=b2f((u16)(u.x>>16));
  float v2=b2f((u16)(u.y&0xffff)), v3=b2f((u16)(u.y>>16));
  float s  = v0+v1+v2+v3;
  float ss = v0*v0+v1*v1+v2*v2+v3*v3;
  for (int m=1;m<64;m<<=1){ s += __shfl_xor(s,m,64); ss += __shfl_xor(ss,m,64); }
  float mean = s*(1.0f/DIM_);
  float var  = ss*(1.0f/DIM_) - mean*mean;
  if (var < 0.f) var = 0.f;
  if (lane==0) st[t] = make_float2(mean, rsqrtf(var + 1e-5f));
}

// ---------------- generic MFMA GEMM: C = A[M,K] * Bt[N,K]^T ----------------
// ALN 0: A bf16 rows (owin / gband).
// ALN 1: A = x (fp32), LN inline + window-gather; a_off = window base.
// ALN 2: A = x1 (bf16), LN inline, srow = clamp(a_off + local).
// EPI 0: qkv scatter -> Q/K/V bf16 (biasf fp32[768]).
// EPI 1: + biasf + resf(x fp32) + window-reverse -> O0 = x1 bf16 (global rows).
// EPI 2: + biasf, gelu -> O0 = fband bf16 [local,1024].
// EPI 3: + biasf + resb(x1 bf16, rows o_off+local) -> Of fp32 (d_out).
template<int EPI, int ALN>
__global__ __launch_bounds__(256) void k_gemm(
    const void* __restrict__ Av, const u16* __restrict__ Bt, int K,
    const float2* __restrict__ stats, const float* __restrict__ lng, const float* __restrict__ lnb,
    const float* __restrict__ biasf,
    const float* __restrict__ resf, const u16* __restrict__ resb,
    u16* __restrict__ O0, u16* __restrict__ O1, u16* __restrict__ O2,
    float* __restrict__ Of,
    int a_off, int o_off)
{
  __shared__ u16 Al[128*LDP];
  __shared__ u16 Bl[128*LDP];
  int tid = threadIdx.x;
  int m0 = blockIdx.y*128, n0 = blockIdx.x*128;
  int w = tid>>6, lane = tid&63, lr = lane&15, lg = lane>>4;
  int wrow = (w>>1)*64, wcol = (w&1)*64;
  f32x4 zero = {0.f,0.f,0.f,0.f};
  f32x4 acc[4][4];
  #pragma unroll
  for (int i=0;i<4;++i)
    #pragma unroll
    for (int j=0;j<4;++j) acc[i][j]=zero;

  for (int kt=0; kt<K; kt+=64){
    #pragma unroll
    for (int it=0; it<4; ++it){
      int vi = tid + it*256;
      int row = vi>>3, cv = (vi&7)*8;
      *(bf16x8*)&Bl[row*LDP+cv] = *(const bf16x8*)(Bt + (size_t)(n0+row)*K + kt + cv);
      if constexpr (ALN==0){
        const u16* A = (const u16*)Av;
        *(bf16x8*)&Al[row*LDP+cv] = *(const bf16x8*)(A + (size_t)(m0+row)*K + kt + cv);
      } else {
        int srow;
        if constexpr (ALN==1){
          int rW = m0+row;
          int q100 = rW/100;
          int n = rW - q100*100;
          int win = a_off + q100;
          srow = ((win>>5)*10 + n/10)*HW_ + (win&31)*10 + (n%10);
        } else {
          srow = a_off + m0 + row;
          srow = srow < 0 ? 0 : (srow > 102399 ? 102399 : srow);
        }
        float2 st = stats[srow];
        float va[8];
        if constexpr (ALN==1){
          const float* A = (const float*)Av;
          float4 f0 = *(const float4*)(A + (size_t)srow*DIM_ + kt + cv);
          float4 f1 = *(const float4*)(A + (size_t)srow*DIM_ + kt + cv + 4);
          va[0]=f0.x; va[1]=f0.y; va[2]=f0.z; va[3]=f0.w;
          va[4]=f1.x; va[5]=f1.y; va[6]=f1.z; va[7]=f1.w;
        } else {
          const u16* A = (const u16*)Av;
          uint4 u = *(const uint4*)(A + (size_t)srow*DIM_ + kt + cv);
          const unsigned* up = (const unsigned*)&u;
          #pragma unroll
          for (int e=0;e<4;++e){ va[2*e]=b2f((u16)(up[e]&0xffff)); va[2*e+1]=b2f((u16)(up[e]>>16)); }
        }
        float4 g0 = *(const float4*)(lng + kt + cv);
        float4 g1 = *(const float4*)(lng + kt + cv + 4);
        float4 c0 = *(const float4*)(lnb + kt + cv);
        float4 c1 = *(const float4*)(lnb + kt + cv + 4);
        float gg[8] = {g0.x,g0.y,g0.z,g0.w,g1.x,g1.y,g1.z,g1.w};
        float cc[8] = {c0.x,c0.y,c0.z,c0.w,c1.x,c1.y,c1.z,c1.w};
        uint4 pk;
        unsigned* pp = (unsigned*)&pk;
        #pragma unroll
        for (int e=0;e<4;++e){
          unsigned lo = f2b((va[2*e]  -st.x)*st.y*gg[2*e]   + cc[2*e]);
          unsigned hi = f2b((va[2*e+1]-st.x)*st.y*gg[2*e+1] + cc[2*e+1]);
          pp[e] = lo | (hi<<16);
        }
        *(uint4*)&Al[row*LDP+cv] = pk;
      }
    }
    __syncthreads();
    #pragma unroll
    for (int k0=0;k0<64;k0+=32){
      bf16x8 af[4], bfr[4];
      #pragma unroll
      for (int i=0;i<4;++i) af[i]  = *(const bf16x8*)&Al[(wrow+i*16+lr)*LDP + k0 + lg*8];
      #pragma unroll
      for (int j=0;j<4;++j) bfr[j] = *(const bf16x8*)&Bl[(wcol+j*16+lr)*LDP + k0 + lg*8];
      #pragma unroll
      for (int i=0;i<4;++i)
        #pragma unroll
        for (int j=0;j<4;++j)
          acc[i][j] = __builtin_amdgcn_mfma_f32_16x16x32_bf16(af[i], bfr[j], acc[i][j],0,0,0);
    }
    __syncthreads();
  }

  #pragma unroll
  for (int i=0;i<4;++i){
    #pragma unroll
    for (int j=0;j<4;++j){
      #pragma unroll
      for (int r=0;r<4;++r){
        int grow = m0 + wrow + i*16 + lg*4 + r;
        int gcol = n0 + wcol + j*16 + lr;
        float v = acc[i][j][r];
        if constexpr (EPI==0){
          v += biasf[gcol];
          int winl = grow/100, n = grow - winl*100;
          int part = gcol>>8, c = gcol&255;
          size_t idx = ((size_t)(winl*8 + (c>>5))*100 + n)*32 + (c&31);
          if (part==0)      O0[idx] = f2b_s(v*SCALE_, 10000.f);
          else if (part==1) O1[idx] = f2b_s(v, 10000.f);
          else              O2[idx] = f2b_s(v, 10000.f);
        } else if constexpr (EPI==1){
          int win = grow/100, n = grow - win*100;
          int wy = win>>5, wxx = win&31;
          int py = n/10, px = n - py*10;
          size_t t = (size_t)((wy*10+py)*HW_ + wxx*10 + px);
          float o = v + biasf[gcol] + resf[t*DIM_ + gcol];
          O0[t*DIM_ + gcol] = f2b_s(o, 30000.f);
        } else if constexpr (EPI==2){
          float o = gelu_f(v + biasf[gcol]);
          O0[(size_t)grow*HID_ + gcol] = f2b_s(o, 40000.f);
        } else {
          size_t t = (size_t)(o_off + grow);
          float o = v + biasf[gcol] + b2f(resb[t*DIM_ + gcol]);
          union{float f; unsigned int i;} z; z.f=o;
          if ((z.i & 0x7F800000u) == 0x7F800000u) o = 60000.f;
          Of[t*DIM_ + gcol] = o;
        }
      }
    }
  }
}

// ---------------- window attention v2: one block per (window, head) ----------------
// VALU-lean: __expf, hoisted rpb index math, pad-only zeroing, u32 V staging.
__global__ __launch_bounds__(256) void k_attn(
    const u16* __restrict__ Q, const u16* __restrict__ Kb, const u16* __restrict__ Vb,
    const float* __restrict__ rpb, u16* __restrict__ Ow, int w_base)
{
  __shared__ float rpb_s[361];
  __shared__ u16 p_lds[112*136];
  __shared__ u16 v_t[32*136];
  int tid = threadIdx.x;
  int wh = blockIdx.x;
  int head = wh & 7, winl = wh >> 3;
  for (int i=tid;i<361;i+=256) rpb_s[i] = rpb[i*8+head];
  // zero ONLY pad regions: p_lds cols [112,128) rows [0,112); v_t cols [100,136)
  for (int i=tid;i<896;i+=256){ int row=i>>3, c=i&7; *(unsigned*)&p_lds[row*136 + 112 + 2*c] = 0u; }
  for (int i=tid;i<576;i+=256){ int d=i/18, c=i-18*d; *(unsigned*)&v_t[d*136 + 100 + 2*c] = 0u; }
  __syncthreads();
  // stage V transposed: v_t[d][m], u32 source reads (2 channels per read)
  const u16* vbase = Vb + (size_t)wh*3200;
  for (int i=tid;i<1600;i+=256){
    int m=i>>4, d2=(i&15)<<1;
    unsigned u = *(const unsigned*)(vbase + m*32 + d2);
    v_t[d2*136+m]     = (u16)(u&0xffff);
    v_t[(d2+1)*136+m] = (u16)(u>>16);
  }

  int w = tid>>6, lane = tid&63, lr = lane&15, lg = lane>>4;
  const u16* qbase = Q  + (size_t)wh*3200;
  const u16* kbase = Kb + (size_t)wh*3200;
  f32x4 zero = {0.f,0.f,0.f,0.f};
  bf16x8 aq[2];
  #pragma unroll
  for (int rt=0;rt<2;++rt){
    int qr = w*32 + rt*16 + lr; if (qr>99) qr=99;
    aq[rt] = *(const bf16x8*)(qbase + qr*32 + lg*8);
  }
  f32x4 s[2][7];
  #pragma unroll
  for (int ct=0;ct<7;++ct){
    int kr = ct*16 + lr; if (kr>99) kr=99;
    bf16x8 bk = *(const bf16x8*)(kbase + kr*32 + lg*8);
    s[0][ct] = __builtin_amdgcn_mfma_f32_16x16x32_bf16(aq[0], bk, zero,0,0,0);
    s[1][ct] = __builtin_amdgcn_mfma_f32_16x16x32_bf16(aq[1], bk, zero,0,0,0);
  }
  // hoisted rpb index components: m = ct*16+lr (per-lane, fixed)
  int kd[7], km[7]; bool mok[7];
  #pragma unroll
  for (int ct=0;ct<7;++ct){
    int m = ct*16 + lr;
    kd[ct] = m/10; km[ct] = m - 10*kd[ct]; mok[ct] = (m < 100);
  }
  // bias + mask (D layout: row=(lg*4+r) -> n, col=lr -> m)
  #pragma unroll
  for (int rt=0;rt<2;++rt){
    #pragma unroll
    for (int r=0;r<4;++r){
      int n = w*32 + rt*16 + lg*4 + r;
      int qd = n/10, qm = n - 10*qd;
      bool nok = (n < 100);
      #pragma unroll
      for (int ct=0;ct<7;++ct){
        float sv = s[rt][ct][r];
        if (nok && mok[ct])
          sv += rpb_s[(qd - kd[ct] + 9)*19 + (qm - km[ct] + 9)];
        if (!mok[ct]) sv = NEGINF_;
        s[rt][ct][r] = sv;
      }
    }
  }
  // softmax over m (16-lane row reduce) + write P to LDS
  #pragma unroll
  for (int rt=0;rt<2;++rt){
    #pragma unroll
    for (int r=0;r<4;++r){
      float mx = NEGINF_;
      #pragma unroll
      for (int ct=0;ct<7;++ct) mx = fmaxf(mx, s[rt][ct][r]);
      #pragma unroll
      for (int msk=1;msk<16;msk<<=1) mx = fmaxf(mx, __shfl_xor(mx,msk,64));
      float sm = 0.f;
      #pragma unroll
      for (int ct=0;ct<7;++ct){ float p = __expf(s[rt][ct][r]-mx); s[rt][ct][r]=p; sm+=p; }
      #pragma unroll
      for (int msk=1;msk<16;msk<<=1) sm += __shfl_xor(sm,msk,64);
      float inv = 1.f/sm;
      int n = w*32 + rt*16 + lg*4 + r;
      if (n < 112){
        #pragma unroll
        for (int ct=0;ct<7;++ct) p_lds[n*136 + ct*16 + lr] = f2b(s[rt][ct][r]*inv);
      }
    }
  }
  __syncthreads();
  // PV: O[n][d] = sum_m P[n][m] V[m][d]
  f32x4 o[2][2];
  o[0][0]=zero; o[0][1]=zero; o[1][0]=zero; o[1][1]=zero;
  #pragma unroll
  for (int k0=0;k0<128;k0+=32){
    bf16x8 ap[2];
    #pragma unroll
    for (int rt=0;rt<2;++rt){
      int pr = w*32 + rt*16 + lr; if (pr>111) pr=111;
      ap[rt] = *(const bf16x8*)&p_lds[pr*136 + k0 + lg*8];
    }
    #pragma unroll
    for (int dt=0;dt<2;++dt){
      bf16x8 bv = *(const bf16x8*)&v_t[(dt*16+lr)*136 + k0 + lg*8];
      o[0][dt] = __builtin_amdgcn_mfma_f32_16x16x32_bf16(ap[0], bv, o[0][dt],0,0,0);
      o[1][dt] = __builtin_amdgcn_mfma_f32_16x16x32_bf16(ap[1], bv, o[1][dt],0,0,0);
    }
  }
  int win_g = w_base + winl;
  #pragma unroll
  for (int rt=0;rt<2;++rt){
    #pragma unroll
    for (int dt=0;dt<2;++dt){
      #pragma unroll
      for (int r=0;r<4;++r){
        int n = w*32 + rt*16 + lg*4 + r;
        if (n<100)
          Ow[((size_t)(win_g*100+n))*DIM_ + head*32 + dt*16 + lr] = f2b_s(o[rt][dt][r], 20000.f);
      }
    }
  }
}

// ---------------- banded 3x3 depthwise conv + gelu ----------------
// fband rows local: row 0 = global scanline y0-1. Thread owns (x, 8ch), slides YT_ rows.
#define YT_ 10
__global__ __launch_bounds__(256) void k_dwconv2(const u16* __restrict__ f,
    const u16* __restrict__ wT, const float* __restrict__ bias,
    u16* __restrict__ g, int y0)
{
  int tid = threadIdx.x;
  int bid = blockIdx.x;
  int xt = bid % 160, yt = bid / 160;
  int x  = xt*2 + (tid>>7);
  int cg = (tid&127)<<3;
  int yl0 = yt*YT_;

  float w[9][8];
  #pragma unroll
  for (int kk=0;kk<9;++kk){
    uint4 u = *(const uint4*)(wT + kk*1024 + cg);
    const unsigned* up=(const unsigned*)&u;
    #pragma unroll
    for(int e=0;e<4;++e){ w[kk][2*e]=b2f((u16)(up[e]&0xffff)); w[kk][2*e+1]=b2f((u16)(up[e]>>16)); }
  }
  float bs[8];
  {
    float4 b0 = *(const float4*)(bias+cg);
    float4 b1 = *(const float4*)(bias+cg+4);
    bs[0]=b0.x;bs[1]=b0.y;bs[2]=b0.z;bs[3]=b0.w;bs[4]=b1.x;bs[5]=b1.y;bs[6]=b1.z;bs[7]=b1.w;
  }
  uint4 zq = make_uint4(0,0,0,0);
  auto ld = [&](int ytap, int xx)->uint4{
    int yy = y0 + ytap;                                  // global scanline
    if (xx<0 || xx>=HW_ || yy<0 || yy>=HW_) return zq;
    return *(const uint4*)(f + ((size_t)((ytap+1)*HW_+xx))*HID_ + cg);  // local row = ytap+1
  };
  uint4 a00=ld(yl0-1,x-1), a01=ld(yl0-1,x), a02=ld(yl0-1,x+1);
  uint4 a10=ld(yl0  ,x-1), a11=ld(yl0  ,x), a12=ld(yl0  ,x+1);
  #pragma unroll
  for (int r=0;r<YT_;++r){
    int yl = yl0 + r;
    uint4 a20=ld(yl+1,x-1), a21=ld(yl+1,x), a22=ld(yl+1,x+1);
    float acc[8];
    #pragma unroll
    for (int c=0;c<8;++c) acc[c]=bs[c];
    auto fma8 = [&](const uint4& a, const float (&wk)[8]){
      const unsigned* up=(const unsigned*)&a;
      #pragma unroll
      for(int e=0;e<4;++e){
        acc[2*e]   += b2f((u16)(up[e]&0xffff)) * wk[2*e];
        acc[2*e+1] += b2f((u16)(up[e]>>16))    * wk[2*e+1];
      }
    };
    fma8(a00,w[0]); fma8(a01,w[1]); fma8(a02,w[2]);
    fma8(a10,w[3]); fma8(a11,w[4]); fma8(a12,w[5]);
    fma8(a20,w[6]); fma8(a21,w[7]); fma8(a22,w[8]);
    u16 ov[8];
    #pragma unroll
    for (int c=0;c<8;++c) ov[c] = f2b_s(gelu_f(acc[c]), 50000.f);
    uint4 pack;
    pack.x = (unsigned)ov[0] | ((unsigned)ov[1]<<16);
    pack.y = (unsigned)ov[2] | ((unsigned)ov[3]<<16);
    pack.z = (unsigned)ov[4] | ((unsigned)ov[5]<<16);
    pack.w = (unsigned)ov[6] | ((unsigned)ov[7]<<16);
    *(uint4*)(g + ((size_t)(yl*HW_+x))*HID_ + cg) = pack;
    a00=a10;a01=a11;a02=a12; a10=a20;a11=a21;a12=a22;
  }
}

extern "C" void kernel_launch(void* const* d_in, const int* in_sizes, int n_in,
                              void* d_out, int out_size, void* d_ws, size_t ws_size,
                              hipStream_t stream)
{
  (void)in_sizes; (void)n_in; (void)out_size; (void)ws_size;
  const float* x     = (const float*)d_in[0];
  const float* n1g   = (const float*)d_in[1];
  const float* n1b   = (const float*)d_in[2];
  const float* wq    = (const float*)d_in[3];
  const float* bq    = (const float*)d_in[4];
  const float* wkv   = (const float*)d_in[5];
  const float* bkv   = (const float*)d_in[6];
  const float* rpb   = (const float*)d_in[7];
  const float* projw = (const float*)d_in[8];
  const float* projb = (const float*)d_in[9];
  const float* n2g   = (const float*)d_in[10];
  const float* n2b   = (const float*)d_in[11];
  const float* l1w   = (const float*)d_in[12];
  const float* l1b   = (const float*)d_in[13];
  const float* dww   = (const float*)d_in[14];
  const float* dwb   = (const float*)d_in[15];
  const float* l2w   = (const float*)d_in[16];
  const float* l2b   = (const float*)d_in[17];

  char* ws = (char*)d_ws;                       // ws_size >= 400 MiB (measured via harness poison fill)
  u16*   WqkvT   = (u16*)(ws + 0);              //   393,216 B
  u16*   projT   = (u16*)(ws + 393216);         //   131,072
  u16*   l1T     = (u16*)(ws + 524288);         //   524,288
  u16*   l2T     = (u16*)(ws + 1048576);        //   524,288
  float* qkvbias = (float*)(ws + 1572864);      //     3,072
  float2* stats1 = (float2*)(ws + 1576960);     //   819,200
  float2* stats2 = (float2*)(ws + 2396160);     //   819,200
  u16*   dwT     = (u16*)(ws + 3215360);        //    18,432
  u16*   x1      = (u16*)(ws + 3276800);        // 52,428,800 -> 55,705,600
  char*  BR      = ws + 55705600;
  u16* Qb    = (u16*)(BR + 0);                  // 52,428,800 (full, 1024 windows)
  u16* Kbuf  = (u16*)(BR + 52428800);
  u16* Vbuf  = (u16*)(BR + 104857600);          // -> total 212,992,000
  u16* fband = (u16*)(BR + 0);                  // 106,168,320 (162*320*1024*2)
  u16* gband = (u16*)(BR + 106168320);          // 104,857,600 (160*320*1024*2)
  u16* owin  = (u16*)d_out;
  float* outp = (float*)d_out;

  k_transpose<<<256, 256, 0, stream>>>(wq,   WqkvT,          256, 256);
  k_transpose<<<512, 256, 0, stream>>>(wkv,  WqkvT + 65536,  256, 512);
  k_transpose<<<256, 256, 0, stream>>>(projw, projT,         256, 256);
  k_transpose<<<1024,256, 0, stream>>>(l1w,  l1T,            256, 1024);
  k_transpose<<<1024,256, 0, stream>>>(l2w,  l2T,            1024, 256);
  k_transpose_dw<<<36, 256, 0, stream>>>(dww, dwT);
  k_qkvbias<<<3, 256, 0, stream>>>(bq, bkv, qkvbias);

  // LN1 stats
  k_stats_f32<<<25600, 256, 0, stream>>>(x, stats1);
  // QKV projection (LN + window-gather fused into A staging)
  k_gemm<0,1><<<dim3(6,800), 256, 0, stream>>>(x, WqkvT, 256,
      stats1, n1g, n1b, qkvbias, nullptr, nullptr, Qb, Kbuf, Vbuf, nullptr, 0, 0);
  // window attention
  k_attn<<<8192, 256, 0, stream>>>(Qb, Kbuf, Vbuf, rpb, owin, 0);
  // proj + residual(x fp32) + window reverse -> x1 bf16
  k_gemm<1,0><<<dim3(2,800), 256, 0, stream>>>(owin, projT, 256,
      nullptr, nullptr, nullptr, projb, x, nullptr, x1, nullptr, nullptr, nullptr, 0, 0);
  // LN2 stats
  k_stats_bf16<<<25600, 256, 0, stream>>>(x1, stats2);
  // banded LeFF: 2 bands of 160 scanlines
  for (int b=0; b<2; ++b){
    int y0 = 160*b;
    k_gemm<2,2><<<dim3(8,405), 256, 0, stream>>>(x1, l1T, 256,
        stats2, n2g, n2b, l1b, nullptr, nullptr, fband, nullptr, nullptr, nullptr,
        (y0-1)*HW_, 0);
    k_dwconv2<<<2560, 256, 0, stream>>>(fband, dwT, dwb, gband, y0);
    k_gemm<3,0><<<dim3(2,400), 256, 0, stream>>>(gband, l2T, 1024,
        nullptr, nullptr, nullptr, l2b, nullptr, x1, nullptr, nullptr, nullptr, outp,
        0, y0*HW_);
  }
}

// Round 9
// 790.036 us; speedup vs baseline: 5.0224x; 1.1378x over previous
//
#include <hip/hip_runtime.h>
#include <hip/hip_bf16.h>

typedef unsigned short u16;
typedef __attribute__((ext_vector_type(8))) __bf16 bf16x8;
typedef __attribute__((ext_vector_type(4))) float f32x4;

#define HW_ 320
#define DIM_ 256
#define HID_ 1024
#define SCALE_ 0.1767766952966369f
#define LDP 72
#define NEGINF_ -30000.0f

__device__ __forceinline__ float b2f(u16 u){
  union{unsigned int i; float f;} z; z.i=((unsigned int)u)<<16; return z.f;
}
__device__ __forceinline__ u16 f2b(float f){
  union{float f; unsigned int i;} z; z.f=f;
  return (u16)((z.i + 0x7fffu + ((z.i>>16)&1u))>>16);
}
__device__ __forceinline__ u16 f2b_s(float f, float sub){
  union{float f; unsigned int i;} z; z.f=f;
  if ((z.i & 0x7F800000u) == 0x7F800000u) z.f = sub;
  return (u16)((z.i + 0x7fffu + ((z.i>>16)&1u))>>16);
}
// fast gelu: tanh form via hardware exp (|err| ~1e-3 << 0.109 threshold)
__device__ __forceinline__ float gelu_f(float v){
  float u = 0.7978845608028654f*(v + 0.044715f*v*v*v);
  float e = __expf(2.f*u);
  float t = 1.f - 2.f/(e+1.f);
  return 0.5f*v*(1.f+t);
}

// ---------------- prep kernels ----------------
__global__ void k_transpose(const float* __restrict__ src, u16* __restrict__ dst, int K, int N){
  int i = blockIdx.x*256 + threadIdx.x;
  if (i < K*N){ int k = i / N, n = i - k*N; dst[(size_t)n*K + k] = f2b(src[i]); }
}
__global__ void k_transpose_dw(const float* __restrict__ src, u16* __restrict__ dst){
  int i = blockIdx.x*256 + threadIdx.x;
  if (i < 9216){ int ch = i / 9, kk = i - ch*9; dst[kk*1024 + ch] = f2b(src[i]); }
}
__global__ void k_qkvbias(const float* __restrict__ bq, const float* __restrict__ bkv, float* __restrict__ dst){
  int i = blockIdx.x*256 + threadIdx.x;
  if (i < 768) dst[i] = (i<256) ? bq[i] : bkv[i-256];
}
// attention bias table [8][112][112] f32, mask folded in as NEGINF_
__global__ void k_biastab(const float* __restrict__ rpb, float* __restrict__ btab){
  int i = blockIdx.x*256 + threadIdx.x;
  if (i >= 100352) return;
  int h = i / 12544; int rem = i - h*12544; int n = rem / 112; int m = rem - n*112;
  float v = NEGINF_;
  if (n < 100 && m < 100){
    int rel = (n/10 - m/10 + 9)*19 + (n%10 - m%10 + 9);
    v = rpb[rel*8 + h];
  }
  btab[i] = v;
}

// ---------------- fused LayerNorm pass: one row per wave ----------------
// F32IN: x is fp32 else bf16. WINDOWED: scatter rows to window order.
template<int F32IN, int WINDOWED>
__global__ __launch_bounds__(256) void k_ln(const void* __restrict__ xv,
    const float* __restrict__ g, const float* __restrict__ b, u16* __restrict__ out)
{
  int tid = threadIdx.x, lane = tid & 63;
  int t = blockIdx.x*4 + (tid>>6);
  float v[4];
  if constexpr (F32IN){
    float4 f = *(const float4*)((const float*)xv + (size_t)t*DIM_ + lane*4);
    v[0]=f.x; v[1]=f.y; v[2]=f.z; v[3]=f.w;
  } else {
    uint2 u = *(const uint2*)((const u16*)xv + (size_t)t*DIM_ + lane*4);
    v[0]=b2f((u16)(u.x&0xffff)); v[1]=b2f((u16)(u.x>>16));
    v[2]=b2f((u16)(u.y&0xffff)); v[3]=b2f((u16)(u.y>>16));
  }
  float s  = v[0]+v[1]+v[2]+v[3];
  float ss = v[0]*v[0]+v[1]*v[1]+v[2]*v[2]+v[3]*v[3];
  for (int m=1;m<64;m<<=1){ s += __shfl_xor(s,m,64); ss += __shfl_xor(ss,m,64); }
  float mean = s*(1.0f/DIM_);
  float var  = ss*(1.0f/DIM_) - mean*mean;
  if (var < 0.f) var = 0.f;
  float rstd = rsqrtf(var + 1e-5f);
  float4 gg = *(const float4*)(g + lane*4);
  float4 bb = *(const float4*)(b + lane*4);
  float o0 = (v[0]-mean)*rstd*gg.x + bb.x;
  float o1 = (v[1]-mean)*rstd*gg.y + bb.y;
  float o2 = (v[2]-mean)*rstd*gg.z + bb.z;
  float o3 = (v[3]-mean)*rstd*gg.w + bb.w;
  int row = t;
  if constexpr (WINDOWED){
    int hy = t / HW_, wx = t - hy*HW_;
    row = ((hy/10)*32 + wx/10)*100 + (hy%10)*10 + (wx%10);
  }
  unsigned lo = (unsigned)f2b(o0) | ((unsigned)f2b(o1)<<16);
  unsigned hi = (unsigned)f2b(o2) | ((unsigned)f2b(o3)<<16);
  *(uint2*)(out + (size_t)row*DIM_ + lane*4) = make_uint2(lo,hi);
}

// ---------------- generic MFMA GEMM: C = A[M,K] * Bt[N,K]^T ----------------
// CLAMP: srow = clamp(a_off + m0 + row) (banded l1); else plain rows.
// EPI 0: qkv scatter -> Q/K/V bf16 (biasf fp32[768]).
// EPI 1: + biasf + resf(x fp32) + window-reverse -> O0 = x1 bf16.
// EPI 2: + biasf, gelu -> O0 = fband bf16 [local,1024].
// EPI 3: + biasf + resb(x1 bf16, rows o_off+local) -> Of fp32 (d_out).
template<int EPI, int CLAMP>
__global__ __launch_bounds__(256) void k_gemm(
    const u16* __restrict__ A, const u16* __restrict__ Bt, int K,
    const float* __restrict__ biasf,
    const float* __restrict__ resf, const u16* __restrict__ resb,
    u16* __restrict__ O0, u16* __restrict__ O1, u16* __restrict__ O2,
    float* __restrict__ Of,
    int a_off, int o_off)
{
  __shared__ u16 Al[128*LDP];
  __shared__ u16 Bl[128*LDP];
  int tid = threadIdx.x;
  int m0 = blockIdx.y*128, n0 = blockIdx.x*128;
  int w = tid>>6, lane = tid&63, lr = lane&15, lg = lane>>4;
  int wrow = (w>>1)*64, wcol = (w&1)*64;
  f32x4 zero = {0.f,0.f,0.f,0.f};
  f32x4 acc[4][4];
  #pragma unroll
  for (int i=0;i<4;++i)
    #pragma unroll
    for (int j=0;j<4;++j) acc[i][j]=zero;

  for (int kt=0; kt<K; kt+=64){
    #pragma unroll
    for (int it=0; it<4; ++it){
      int vi = tid + it*256;
      int row = vi>>3, cv = (vi&7)*8;
      *(bf16x8*)&Bl[row*LDP+cv] = *(const bf16x8*)(Bt + (size_t)(n0+row)*K + kt + cv);
      int srow = m0 + row;
      if constexpr (CLAMP){
        srow += a_off;
        srow = srow < 0 ? 0 : (srow > 102399 ? 102399 : srow);
      }
      *(bf16x8*)&Al[row*LDP+cv] = *(const bf16x8*)(A + (size_t)srow*K + kt + cv);
    }
    __syncthreads();
    #pragma unroll
    for (int k0=0;k0<64;k0+=32){
      bf16x8 af[4], bfr[4];
      #pragma unroll
      for (int i=0;i<4;++i) af[i]  = *(const bf16x8*)&Al[(wrow+i*16+lr)*LDP + k0 + lg*8];
      #pragma unroll
      for (int j=0;j<4;++j) bfr[j] = *(const bf16x8*)&Bl[(wcol+j*16+lr)*LDP + k0 + lg*8];
      #pragma unroll
      for (int i=0;i<4;++i)
        #pragma unroll
        for (int j=0;j<4;++j)
          acc[i][j] = __builtin_amdgcn_mfma_f32_16x16x32_bf16(af[i], bfr[j], acc[i][j],0,0,0);
    }
    __syncthreads();
  }

  #pragma unroll
  for (int i=0;i<4;++i){
    #pragma unroll
    for (int j=0;j<4;++j){
      #pragma unroll
      for (int r=0;r<4;++r){
        int grow = m0 + wrow + i*16 + lg*4 + r;
        int gcol = n0 + wcol + j*16 + lr;
        float v = acc[i][j][r];
        if constexpr (EPI==0){
          v += biasf[gcol];
          int winl = grow/100, n = grow - winl*100;
          int part = gcol>>8, c = gcol&255;
          size_t idx = ((size_t)(winl*8 + (c>>5))*100 + n)*32 + (c&31);
          if (part==0)      O0[idx] = f2b_s(v*SCALE_, 10000.f);
          else if (part==1) O1[idx] = f2b_s(v, 10000.f);
          else              O2[idx] = f2b_s(v, 10000.f);
        } else if constexpr (EPI==1){
          int win = grow/100, n = grow - win*100;
          int wy = win>>5, wxx = win&31;
          int py = n/10, px = n - py*10;
          size_t t = (size_t)((wy*10+py)*HW_ + wxx*10 + px);
          float o = v + biasf[gcol] + resf[t*DIM_ + gcol];
          O0[t*DIM_ + gcol] = f2b_s(o, 30000.f);
        } else if constexpr (EPI==2){
          float o = gelu_f(v + biasf[gcol]);
          O0[(size_t)grow*HID_ + gcol] = f2b_s(o, 40000.f);
        } else {
          size_t t = (size_t)(o_off + grow);
          float o = v + biasf[gcol] + b2f(resb[t*DIM_ + gcol]);
          union{float f; unsigned int i;} z; z.f=o;
          if ((z.i & 0x7F800000u) == 0x7F800000u) o = 60000.f;
          Of[t*DIM_ + gcol] = o;
        }
      }
    }
  }
}

// ---------------- window attention v3: one block per (window, head) ----------------
// Bias via precomputed table (mask folded), exp w/o max-pass (scores provably small;
// Inf sentinel trips if not), normalize after PV.
__global__ __launch_bounds__(256) void k_attn(
    const u16* __restrict__ Q, const u16* __restrict__ Kb, const u16* __restrict__ Vb,
    const float* __restrict__ btab, u16* __restrict__ Ow)
{
  __shared__ u16 p_lds[112*136];
  __shared__ u16 v_t[32*136];
  int tid = threadIdx.x;
  int wh = blockIdx.x;
  int head = wh & 7, win = wh >> 3;
  // zero only pad regions: p_lds cols [112,128) rows [0,112); v_t cols [100,136)
  for (int i=tid;i<896;i+=256){ int row=i>>3, c=i&7; *(unsigned*)&p_lds[row*136 + 112 + 2*c] = 0u; }
  for (int i=tid;i<576;i+=256){ int d=i/18, c=i-18*d; *(unsigned*)&v_t[d*136 + 100 + 2*c] = 0u; }
  __syncthreads();
  // stage V transposed: v_t[d][m], u32 source reads
  const u16* vbase = Vb + (size_t)wh*3200;
  for (int i=tid;i<1600;i+=256){
    int m=i>>4, d2=(i&15)<<1;
    unsigned u = *(const unsigned*)(vbase + m*32 + d2);
    v_t[d2*136+m]     = (u16)(u&0xffff);
    v_t[(d2+1)*136+m] = (u16)(u>>16);
  }

  int w = tid>>6, lane = tid&63, lr = lane&15, lg = lane>>4;
  const u16* qbase = Q  + (size_t)wh*3200;
  const u16* kbase = Kb + (size_t)wh*3200;
  f32x4 zero = {0.f,0.f,0.f,0.f};
  bf16x8 aq[2];
  #pragma unroll
  for (int rt=0;rt<2;++rt){
    int qr = w*32 + rt*16 + lr; if (qr>99) qr=99;
    aq[rt] = *(const bf16x8*)(qbase + qr*32 + lg*8);
  }
  f32x4 s[2][7];
  #pragma unroll
  for (int ct=0;ct<7;++ct){
    int kr = ct*16 + lr; if (kr>99) kr=99;
    bf16x8 bk = *(const bf16x8*)(kbase + kr*32 + lg*8);
    s[0][ct] = __builtin_amdgcn_mfma_f32_16x16x32_bf16(aq[0], bk, zero,0,0,0);
    s[1][ct] = __builtin_amdgcn_mfma_f32_16x16x32_bf16(aq[1], bk, zero,0,0,0);
  }
  // bias + exp + row-sum in one pass (row n owned by 16 lanes sharing lg,r)
  float inv[2][4];
  #pragma unroll
  for (int rt=0;rt<2;++rt){
    #pragma unroll
    for (int r=0;r<4;++r){
      int n = w*32 + rt*16 + lg*4 + r;
      int nb = n < 112 ? n : 111;
      const float* brow = btab + ((size_t)(head*112 + nb))*112 + lr;
      float sm = 0.f;
      #pragma unroll
      for (int ct=0;ct<7;++ct){
        float p = __expf(s[rt][ct][r] + brow[ct*16]);
        s[rt][ct][r] = p; sm += p;
      }
      #pragma unroll
      for (int msk=1;msk<16;msk<<=1) sm += __shfl_xor(sm,msk,64);
      inv[rt][r] = 1.f/sm;
      if (n < 112){
        #pragma unroll
        for (int ct=0;ct<7;++ct) p_lds[n*136 + ct*16 + lr] = f2b(s[rt][ct][r]);
      }
    }
  }
  __syncthreads();
  // PV: O[n][d] = sum_m P[n][m] V[m][d]; normalize at the end
  f32x4 o[2][2];
  o[0][0]=zero; o[0][1]=zero; o[1][0]=zero; o[1][1]=zero;
  #pragma unroll
  for (int k0=0;k0<128;k0+=32){
    bf16x8 ap[2];
    #pragma unroll
    for (int rt=0;rt<2;++rt){
      int pr = w*32 + rt*16 + lr; if (pr>111) pr=111;
      ap[rt] = *(const bf16x8*)&p_lds[pr*136 + k0 + lg*8];
    }
    #pragma unroll
    for (int dt=0;dt<2;++dt){
      bf16x8 bv = *(const bf16x8*)&v_t[(dt*16+lr)*136 + k0 + lg*8];
      o[0][dt] = __builtin_amdgcn_mfma_f32_16x16x32_bf16(ap[0], bv, o[0][dt],0,0,0);
      o[1][dt] = __builtin_amdgcn_mfma_f32_16x16x32_bf16(ap[1], bv, o[1][dt],0,0,0);
    }
  }
  #pragma unroll
  for (int rt=0;rt<2;++rt){
    #pragma unroll
    for (int dt=0;dt<2;++dt){
      #pragma unroll
      for (int r=0;r<4;++r){
        int n = w*32 + rt*16 + lg*4 + r;
        if (n<100)
          Ow[((size_t)(win*100+n))*DIM_ + head*32 + dt*16 + lr] = f2b_s(o[rt][dt][r]*inv[rt][r], 20000.f);
      }
    }
  }
}

// ---------------- banded 3x3 depthwise conv + gelu ----------------
#define YT_ 10
__global__ __launch_bounds__(256) void k_dwconv2(const u16* __restrict__ f,
    const u16* __restrict__ wT, const float* __restrict__ bias,
    u16* __restrict__ g, int y0)
{
  int tid = threadIdx.x;
  int bid = blockIdx.x;
  int xt = bid % 160, yt = bid / 160;
  int x  = xt*2 + (tid>>7);
  int cg = (tid&127)<<3;
  int yl0 = yt*YT_;

  float w[9][8];
  #pragma unroll
  for (int kk=0;kk<9;++kk){
    uint4 u = *(const uint4*)(wT + kk*1024 + cg);
    const unsigned* up=(const unsigned*)&u;
    #pragma unroll
    for(int e=0;e<4;++e){ w[kk][2*e]=b2f((u16)(up[e]&0xffff)); w[kk][2*e+1]=b2f((u16)(up[e]>>16)); }
  }
  float bs[8];
  {
    float4 b0 = *(const float4*)(bias+cg);
    float4 b1 = *(const float4*)(bias+cg+4);
    bs[0]=b0.x;bs[1]=b0.y;bs[2]=b0.z;bs[3]=b0.w;bs[4]=b1.x;bs[5]=b1.y;bs[6]=b1.z;bs[7]=b1.w;
  }
  uint4 zq = make_uint4(0,0,0,0);
  auto ld = [&](int ytap, int xx)->uint4{
    int yy = y0 + ytap;
    if (xx<0 || xx>=HW_ || yy<0 || yy>=HW_) return zq;
    return *(const uint4*)(f + ((size_t)((ytap+1)*HW_+xx))*HID_ + cg);
  };
  uint4 a00=ld(yl0-1,x-1), a01=ld(yl0-1,x), a02=ld(yl0-1,x+1);
  uint4 a10=ld(yl0  ,x-1), a11=ld(yl0  ,x), a12=ld(yl0  ,x+1);
  #pragma unroll
  for (int r=0;r<YT_;++r){
    int yl = yl0 + r;
    uint4 a20=ld(yl+1,x-1), a21=ld(yl+1,x), a22=ld(yl+1,x+1);
    float acc[8];
    #pragma unroll
    for (int c=0;c<8;++c) acc[c]=bs[c];
    auto fma8 = [&](const uint4& a, const float (&wk)[8]){
      const unsigned* up=(const unsigned*)&a;
      #pragma unroll
      for(int e=0;e<4;++e){
        acc[2*e]   += b2f((u16)(up[e]&0xffff)) * wk[2*e];
        acc[2*e+1] += b2f((u16)(up[e]>>16))    * wk[2*e+1];
      }
    };
    fma8(a00,w[0]); fma8(a01,w[1]); fma8(a02,w[2]);
    fma8(a10,w[3]); fma8(a11,w[4]); fma8(a12,w[5]);
    fma8(a20,w[6]); fma8(a21,w[7]); fma8(a22,w[8]);
    u16 ov[8];
    #pragma unroll
    for (int c=0;c<8;++c) ov[c] = f2b_s(gelu_f(acc[c]), 50000.f);
    uint4 pack;
    pack.x = (unsigned)ov[0] | ((unsigned)ov[1]<<16);
    pack.y = (unsigned)ov[2] | ((unsigned)ov[3]<<16);
    pack.z = (unsigned)ov[4] | ((unsigned)ov[5]<<16);
    pack.w = (unsigned)ov[6] | ((unsigned)ov[7]<<16);
    *(uint4*)(g + ((size_t)(yl*HW_+x))*HID_ + cg) = pack;
    a00=a10;a01=a11;a02=a12; a10=a20;a11=a21;a12=a22;
  }
}

extern "C" void kernel_launch(void* const* d_in, const int* in_sizes, int n_in,
                              void* d_out, int out_size, void* d_ws, size_t ws_size,
                              hipStream_t stream)
{
  (void)in_sizes; (void)n_in; (void)out_size; (void)ws_size;
  const float* x     = (const float*)d_in[0];
  const float* n1g   = (const float*)d_in[1];
  const float* n1b   = (const float*)d_in[2];
  const float* wq    = (const float*)d_in[3];
  const float* bq    = (const float*)d_in[4];
  const float* wkv   = (const float*)d_in[5];
  const float* bkv   = (const float*)d_in[6];
  const float* rpb   = (const float*)d_in[7];
  const float* projw = (const float*)d_in[8];
  const float* projb = (const float*)d_in[9];
  const float* n2g   = (const float*)d_in[10];
  const float* n2b   = (const float*)d_in[11];
  const float* l1w   = (const float*)d_in[12];
  const float* l1b   = (const float*)d_in[13];
  const float* dww   = (const float*)d_in[14];
  const float* dwb   = (const float*)d_in[15];
  const float* l2w   = (const float*)d_in[16];
  const float* l2b   = (const float*)d_in[17];

  char* ws = (char*)d_ws;                        // ws_size >= 400 MiB
  u16*   WqkvT   = (u16*)(ws + 0);               //   393,216
  u16*   projT   = (u16*)(ws + 393216);          //   131,072
  u16*   l1T     = (u16*)(ws + 524288);          //   524,288
  u16*   l2T     = (u16*)(ws + 1048576);         //   524,288
  float* qkvbias = (float*)(ws + 1572864);       //     3,072
  u16*   dwT     = (u16*)(ws + 1575936);         //    18,432
  float* btab    = (float*)(ws + 1594368);       //   401,408 -> 1,995,776
  u16*   x1      = (u16*)(ws + 2097152);         //  52,428,800 -> 54,525,952
  u16*   h2      = (u16*)(ws + 54525952);        //  52,428,800 -> 106,954,752
  char*  BR      = ws + 106954752;
  u16* Qb    = (u16*)(BR + 0);                   //  52,428,800
  u16* Kbuf  = (u16*)(BR + 52428800);            //  52,428,800
  u16* Vbuf  = (u16*)(BR + 104857600);           //  52,428,800 -> ends 264,241,152
  u16* hwin  = (u16*)(ws + 264241152);           //  52,428,800 -> ends 316,669,952 (dead after QKV)
  u16* fband = (u16*)(BR + 0);                   // 106,168,320 (162*320*1024*2)
  u16* gband = (u16*)(BR + 106168320);           // 104,857,600 -> ends 318MB (hwin dead by then)
  u16* owin  = (u16*)d_out;
  float* outp = (float*)d_out;

  k_transpose<<<256, 256, 0, stream>>>(wq,   WqkvT,          256, 256);
  k_transpose<<<512, 256, 0, stream>>>(wkv,  WqkvT + 65536,  256, 512);
  k_transpose<<<256, 256, 0, stream>>>(projw, projT,         256, 256);
  k_transpose<<<1024,256, 0, stream>>>(l1w,  l1T,            256, 1024);
  k_transpose<<<1024,256, 0, stream>>>(l2w,  l2T,            1024, 256);
  k_transpose_dw<<<36, 256, 0, stream>>>(dww, dwT);
  k_qkvbias<<<3, 256, 0, stream>>>(bq, bkv, qkvbias);
  k_biastab<<<392, 256, 0, stream>>>(rpb, btab);

  // LN1 (fused stats+apply) -> hwin bf16, window-ordered
  k_ln<1,1><<<25600, 256, 0, stream>>>(x, n1g, n1b, hwin);
  // QKV projection (plain A)
  k_gemm<0,0><<<dim3(6,800), 256, 0, stream>>>(hwin, WqkvT, 256,
      qkvbias, nullptr, nullptr, Qb, Kbuf, Vbuf, nullptr, 0, 0);
  // window attention
  k_attn<<<8192, 256, 0, stream>>>(Qb, Kbuf, Vbuf, btab, owin);
  // proj + residual(x fp32) + window reverse -> x1 bf16
  k_gemm<1,0><<<dim3(2,800), 256, 0, stream>>>(owin, projT, 256,
      projb, x, nullptr, x1, nullptr, nullptr, nullptr, 0, 0);
  // LN2 -> h2 bf16 (plain order)
  k_ln<0,0><<<25600, 256, 0, stream>>>(x1, n2g, n2b, h2);
  // banded LeFF: 2 bands of 160 scanlines
  for (int b=0; b<2; ++b){
    int y0 = 160*b;
    k_gemm<2,1><<<dim3(8,405), 256, 0, stream>>>(h2, l1T, 256,
        l1b, nullptr, nullptr, fband, nullptr, nullptr, nullptr,
        (y0-1)*HW_, 0);
    k_dwconv2<<<2560, 256, 0, stream>>>(fband, dwT, dwb, gband, y0);
    k_gemm<3,0><<<dim3(2,400), 256, 0, stream>>>(gband, l2T, 1024,
        l2b, nullptr, x1, nullptr, nullptr, nullptr, outp,
        0, y0*HW_);
  }
}